// Round 1
// baseline (6185.820 us; speedup 1.0000x reference)
//
#include <hip/hip_runtime.h>
#include <hip/hip_bf16.h>
#include <math.h>

typedef unsigned short u16;
typedef __attribute__((ext_vector_type(8))) short s16x8;
typedef __attribute__((ext_vector_type(4))) short s16x4;
typedef __attribute__((ext_vector_type(4))) float f32x4;

#define DEVI static __device__ __forceinline__

DEVI u16 f2bfu(float f) {
    unsigned u = __float_as_uint(f);
    unsigned r = (u + 0x7fffu + ((u >> 16) & 1u)) >> 16;
    return (u16)r;
}
DEVI float bfu2f(u16 u) { return __uint_as_float(((unsigned)u) << 16); }
DEVI float eluf(float x) { return x > 0.f ? x : (expf(x) - 1.f); }
DEVI float sigm(float x) { return 1.f / (1.f + expf(-x)); }

// ---------------------------------------------------------------------------
// GEMM: C(MxN) = A(MxK, row-major bf16) * Bt^T  (Bt stored [N][K] bf16)
// 16x16x32 bf16 MFMA, 4 waves (2x2), BM=32*MF, BN=32*NF, BK=32,
// double-buffered global_load_lds staging (m97-style 2-phase).
// ---------------------------------------------------------------------------
struct GP {
    const u16* A; int lda;
    const u16* Bt;
    float* Cf; u16* Cb; int ldc;
    const float* bias;
    const u16* aux; int auxld;     // EPI3: embR row (pre-offset); EPI4: latsum
    const float* zs;               // EPI5
    const float* zmean; const float* zstd;
    double* accum;
    int K; int gridN;
};

template <int MF, int NF, int EPI, bool DUAL>
__global__ __launch_bounds__(256) void gemm_k(GP p0, GP p1) {
    GP p = (DUAL && blockIdx.y) ? p1 : p0;
    constexpr int BM = 32 * MF, BN = 32 * NF;
    constexpr int ABYTES = BM * 64, BBYTES = BN * 64;

    const int tid = threadIdx.x;
    const int w = tid >> 6, lane = tid & 63;
    const int bid = blockIdx.x;
    const int bn = bid % p.gridN, bm = bid / p.gridN;
    const int r0 = bm * BM, c0 = bn * BN;
    const int wm = w >> 1, wn = w & 1;

    __shared__ __attribute__((aligned(16))) char sm[2 * (ABYTES + BBYTES)];
    __shared__ float ps[4];

    auto stage = [&](int kt, int buf) {
        char* s = sm + buf * (ABYTES + BBYTES);
        const u16* Ag = p.A + (size_t)r0 * p.lda + kt * 32;
#pragma unroll
        for (int it = 0; it < BM / 64; ++it) {
            int bo = it * 4096 + w * 1024 + lane * 16;
            int row = bo >> 6, kg = (bo & 63) >> 4;
            __builtin_amdgcn_global_load_lds(
                (__attribute__((address_space(1))) void*)(void*)(Ag + (size_t)row * p.lda + kg * 8),
                (__attribute__((address_space(3))) void*)(s + bo), 16, 0, 0);
        }
        const u16* Bg = p.Bt + (size_t)c0 * p.K + kt * 32;
        char* sb = s + ABYTES;
#pragma unroll
        for (int it = 0; it < BN / 64; ++it) {
            int bo = it * 4096 + w * 1024 + lane * 16;
            int row = bo >> 6, kg = (bo & 63) >> 4;
            __builtin_amdgcn_global_load_lds(
                (__attribute__((address_space(1))) void*)(void*)(Bg + (size_t)row * p.K + kg * 8),
                (__attribute__((address_space(3))) void*)(sb + bo), 16, 0, 0);
        }
    };

    f32x4 acc[MF][NF];
#pragma unroll
    for (int mf = 0; mf < MF; ++mf)
#pragma unroll
        for (int nf = 0; nf < NF; ++nf) acc[mf][nf] = (f32x4){0.f, 0.f, 0.f, 0.f};

    const int nk = p.K >> 5;
    stage(0, 0);
    asm volatile("s_waitcnt vmcnt(0)" ::: "memory");
    __syncthreads();
    int cur = 0;
    for (int kt = 0; kt < nk; ++kt) {
        if (kt + 1 < nk) stage(kt + 1, cur ^ 1);
        const char* s = sm + cur * (ABYTES + BBYTES);
        s16x8 aF[MF], bF[NF];
#pragma unroll
        for (int mf = 0; mf < MF; ++mf)
            aF[mf] = *(const s16x8*)(s + ((wm * MF + mf) * 16 + (lane & 15)) * 64 + (lane >> 4) * 16);
#pragma unroll
        for (int nf = 0; nf < NF; ++nf)
            bF[nf] = *(const s16x8*)(s + ABYTES + ((wn * NF + nf) * 16 + (lane & 15)) * 64 + (lane >> 4) * 16);
#pragma unroll
        for (int mf = 0; mf < MF; ++mf)
#pragma unroll
            for (int nf = 0; nf < NF; ++nf)
                acc[mf][nf] = __builtin_amdgcn_mfma_f32_16x16x32_bf16(aF[mf], bF[nf], acc[mf][nf], 0, 0, 0);
        asm volatile("s_waitcnt vmcnt(0)" ::: "memory");
        __syncthreads();
        cur ^= 1;
    }

    // epilogue: C/D layout col=lane&15, row=(lane>>4)*4+j  [guide m89]
    const int lrow4 = (lane >> 4) << 2, lcol = lane & 15;
    float lsum = 0.f;
#pragma unroll
    for (int mf = 0; mf < MF; ++mf) {
        int rowb = r0 + (wm * MF + mf) * 16 + lrow4;
#pragma unroll
        for (int nf = 0; nf < NF; ++nf) {
            int col = c0 + (wn * NF + nf) * 16 + lcol;
#pragma unroll
            for (int j = 0; j < 4; ++j) {
                float v = acc[mf][nf][j];
                int r = rowb + j;
                if constexpr (EPI == 0) {
                    p.Cf[(size_t)r * p.ldc + col] = v + p.bias[col];
                } else if constexpr (EPI == 1) {
                    p.Cb[(size_t)r * p.ldc + col] = f2bfu(eluf(v + p.bias[col]));
                } else if constexpr (EPI == 2) {
                    p.Cb[(size_t)r * p.ldc + col] = f2bfu(v + p.bias[col]);
                } else if constexpr (EPI == 3) {
                    float t;
                    if (col < 1024) t = eluf(v + p.bias[col]);
                    else t = eluf(v + bfu2f(p.aux[(size_t)r * p.auxld + (col - 1024)]));
                    p.Cb[(size_t)r * p.ldc + col] = f2bfu(t);
                } else if constexpr (EPI == 4) {
                    p.Cb[(size_t)r * p.ldc + col] = f2bfu(eluf(v + bfu2f(p.aux[(size_t)r * p.auxld + col])));
                } else if constexpr (EPI == 5) {
                    v += p.bias[col];
                    int tt = r >> 8, b = r & 255;
                    int ch = col >> 9;
                    float z = (p.zs[((size_t)b * 64 + tt + 1) * 2048 + col] - p.zmean[ch]) / p.zstd[ch];
                    float d = v - z;
                    lsum += d * d;
                }
            }
        }
    }
    if constexpr (EPI == 5) {
#pragma unroll
        for (int o = 32; o > 0; o >>= 1) lsum += __shfl_down(lsum, o, 64);
        if (lane == 0) ps[w] = lsum;
        __syncthreads();
        if (tid == 0) {
            double s = (double)ps[0] + (double)ps[1] + (double)ps[2] + (double)ps[3];
            atomicAdd(p.accum, s);
        }
    }
}

// ---------------------------------------------------------------------------
// small kernels
// ---------------------------------------------------------------------------
__global__ void k_init(double* acc) { acc[0] = 0.0; acc[1] = 0.0; }

__global__ void k_cast(const float* __restrict__ src, u16* __restrict__ dst, int n4) {
    int i = blockIdx.x * 256 + threadIdx.x;
    if (i >= n4) return;
    f32x4 v = *(const f32x4*)(src + (size_t)i * 4);
    s16x4 o;
    o[0] = (short)f2bfu(v[0]); o[1] = (short)f2bfu(v[1]);
    o[2] = (short)f2bfu(v[2]); o[3] = (short)f2bfu(v[3]);
    *(s16x4*)(dst + (size_t)i * 4) = o;
}

// dst[n][k] = src[k][n]  (dst bf16 [N][K] compact, src f32 row-stride sld)
__global__ void k_transpose(const float* __restrict__ src, int sld, u16* __restrict__ dst, int K) {
    __shared__ float tile[32][33];
    int k0 = blockIdx.x * 32, n0 = blockIdx.y * 32;
    for (int r = threadIdx.y; r < 32; r += 8)
        tile[r][threadIdx.x] = src[(size_t)(k0 + r) * sld + n0 + threadIdx.x];
    __syncthreads();
    for (int r = threadIdx.y; r < 32; r += 8)
        dst[(size_t)(n0 + r) * K + k0 + threadIdx.x] = f2bfu(tile[threadIdx.x][r]);
}

__global__ void k_prep(const float* __restrict__ zsp, const float* __restrict__ zm,
                       const float* __restrict__ zsd, u16* __restrict__ flat) {
    size_t i = ((size_t)blockIdx.x * 256 + threadIdx.x) * 4;
    f32x4 v = *(const f32x4*)(zsp + i);
    int ch = ((int)(i >> 9)) & 3;
    float m = zm[ch], s = zsd[ch];
    s16x4 o;
    o[0] = (short)f2bfu((v[0] - m) / s); o[1] = (short)f2bfu((v[1] - m) / s);
    o[2] = (short)f2bfu((v[2] - m) / s); o[3] = (short)f2bfu((v[3] - m) / s);
    *(s16x4*)(flat + i) = o;
}

// x for step 0 (lat = 0)
__global__ __launch_bounds__(256) void k_xpre0(const float* __restrict__ preW, const float* __restrict__ preb,
                                               const float* __restrict__ actions, u16* __restrict__ xout) {
    int b = blockIdx.x, tid = threadIdx.x;
    __shared__ float as[3];
    if (tid < 3) as[tid] = actions[(size_t)b * 64 * 3 + tid];
    __syncthreads();
    for (int j = tid; j < 1024; j += 256) {
        float s = preb[j] + as[0] * preW[1024 * 1024 + j] + as[1] * preW[1025 * 1024 + j] + as[2] * preW[1026 * 1024 + j];
        xout[(b << 10) + j] = f2bfu(eluf(s));
    }
}

template <bool FIRST>
__global__ __launch_bounds__(256) void k_gru(const float* __restrict__ gx, const float* __restrict__ gh,
                                             const float* __restrict__ bhh, const float* __restrict__ hold,
                                             float* __restrict__ hnew, u16* __restrict__ hallT) {
    int i = blockIdx.x * 256 + threadIdx.x;       // 0 .. 256*2048
    int b = i >> 11, jj = i & 2047;
    size_t g = (size_t)b * 6144;
    float xr = gx[g + jj], xz = gx[g + 2048 + jj], xn = gx[g + 4096 + jj];
    float hr, hz, hn;
    if (FIRST) { hr = bhh[jj]; hz = bhh[2048 + jj]; hn = bhh[4096 + jj]; }
    else { hr = gh[g + jj]; hz = gh[g + 2048 + jj]; hn = gh[g + 4096 + jj]; }
    float r = sigm(xr + hr);
    float u = sigm(xz + hz);
    float n = tanhf(xn + r * hn);
    float h0 = FIRST ? 0.f : hold[i];
    float h = (1.f - u) * n + u * h0;
    hnew[i] = h;
    hallT[i] = f2bfu(h);
}

// softmax/argmax/KL per batch row + fused pre-MLP x for next step
__global__ __launch_bounds__(256) void k_smx(const float* __restrict__ PrPo, int* __restrict__ latidx_t,
                                             double* __restrict__ klacc,
                                             const float* __restrict__ preW, const float* __restrict__ preb,
                                             const float* __restrict__ actions, u16* __restrict__ xout,
                                             int tnext, int do_x) {
    int b = blockIdx.x, tid = threadIdx.x;
    const float* Pr = PrPo + (size_t)b * 2048;
    const float* Po = Pr + 1024;
    __shared__ float klpart[32];
    __shared__ int idxs[32];
    __shared__ float as[3];
    int grp = tid >> 5, c = tid & 31;
#pragma unroll
    for (int it = 0; it < 4; ++it) {
        int l = it * 8 + grp;
        float po = Po[l * 32 + c];
        float pr = Pr[l * 32 + c];
        float mv = po; int mi = c;
#pragma unroll
        for (int o = 16; o > 0; o >>= 1) {
            float ov = __shfl_xor(mv, o, 32);
            int oi = __shfl_xor(mi, o, 32);
            if (ov > mv || (ov == mv && oi < mi)) { mv = ov; mi = oi; }
        }
        float mq = pr;
#pragma unroll
        for (int o = 16; o > 0; o >>= 1) mq = fmaxf(mq, __shfl_xor(mq, o, 32));
        float ep = expf(po - mv), eq = expf(pr - mq);
        float sp = ep, sq = eq;
#pragma unroll
        for (int o = 16; o > 0; o >>= 1) { sp += __shfl_xor(sp, o, 32); sq += __shfl_xor(sq, o, 32); }
        float logp = po - mv - logf(sp);
        float logq = pr - mq - logf(sq);
        float klc = (ep / sp) * (logp - logq);
#pragma unroll
        for (int o = 16; o > 0; o >>= 1) klc += __shfl_xor(klc, o, 32);
        if (c == 0) { klpart[l] = klc; idxs[l] = mi; }
    }
    __syncthreads();
    if (tid == 0) {
        float kl = 0.f;
        for (int l = 0; l < 32; ++l) kl += klpart[l];
        atomicAdd(klacc, (double)fmaxf(kl, 1.0f));   // 0.8*max + 0.2*max
    }
    if (tid < 32) latidx_t[(b << 5) + tid] = idxs[tid];
    if (do_x) {
        if (tid < 3) as[tid] = actions[((size_t)b * 64 + tnext) * 3 + tid];
        __syncthreads();
        for (int j = tid; j < 1024; j += 256) {
            float s = preb[j] + as[0] * preW[1024 * 1024 + j] + as[1] * preW[1025 * 1024 + j] + as[2] * preW[1026 * 1024 + j];
#pragma unroll
            for (int l = 0; l < 32; ++l) s += preW[(size_t)((l << 5) + idxs[l]) * 1024 + j];
            xout[(b << 10) + j] = f2bfu(eluf(s));
        }
    }
}

// latsum[m][j] = db1[j] + sum_l dW1[2048 + l*32 + idx][j]   (bf16 out)
__global__ __launch_bounds__(256) void k_latsum(const float* __restrict__ dW1, const float* __restrict__ db1,
                                                const int* __restrict__ latidx_all, u16* __restrict__ latsum) {
    int m = blockIdx.x, tid = threadIdx.x;
    __shared__ int idxs[32];
    if (tid < 32) idxs[tid] = latidx_all[(size_t)m * 32 + tid];
    __syncthreads();
    for (int j = tid; j < 1024; j += 256) {
        float s = db1[j];
#pragma unroll
        for (int l = 0; l < 32; ++l) s += dW1[(size_t)(2048 + (l << 5) + idxs[l]) * 1024 + j];
        latsum[(size_t)m * 1024 + j] = f2bfu(s);
    }
}

__global__ void k_finalize(const double* acc, float* out) {
    out[0] = (float)(acc[0] / 33030144.0 + acc[1] / 16128.0);
}

// ---------------------------------------------------------------------------
extern "C" void kernel_launch(void* const* d_in, const int* in_sizes, int n_in,
                              void* d_out, int out_size, void* d_ws, size_t ws_size,
                              hipStream_t stream) {
    const float* zs      = (const float*)d_in[0];
    const float* actions = (const float*)d_in[1];
    const float* zmean   = (const float*)d_in[2];
    const float* zstd    = (const float*)d_in[3];
    const float* encW    = (const float*)d_in[4];
    const float* encb    = (const float*)d_in[5];
    const float* preW    = (const float*)d_in[6];
    const float* preb    = (const float*)d_in[7];
    const float* Wih     = (const float*)d_in[8];
    const float* Whh     = (const float*)d_in[9];
    const float* bih     = (const float*)d_in[10];
    const float* bhh     = (const float*)d_in[11];
    const float* tW1     = (const float*)d_in[12];
    const float* tb1     = (const float*)d_in[13];
    const float* tW2     = (const float*)d_in[14];
    const float* tb2     = (const float*)d_in[15];
    const float* rW1     = (const float*)d_in[16];
    const float* rb1     = (const float*)d_in[17];
    const float* rW2     = (const float*)d_in[18];
    const float* rb2     = (const float*)d_in[19];
    const float* dW1     = (const float*)d_in[20];
    const float* db1     = (const float*)d_in[21];
    const float* dW2     = (const float*)d_in[22];
    const float* db2     = (const float*)d_in[23];

    char* W = (char*)d_ws;
    size_t off = 0;
    auto take = [&](size_t b) { char* p = W + off; off += (b + 255) & ~(size_t)255; return p; };

    double* accum  = (double*)take(16);
    u16* encWbt = (u16*)take((size_t)1024 * 2048 * 2);
    u16* WihB   = (u16*)take((size_t)6144 * 1024 * 2);
    u16* WhhB   = (u16*)take((size_t)6144 * 2048 * 2);
    u16* l1B    = (u16*)take((size_t)2048 * 2048 * 2);
    u16* tW2bt  = (u16*)take((size_t)1024 * 1024 * 2);
    u16* rW2bt  = (u16*)take((size_t)1024 * 1024 * 2);
    u16* rW1bbt = (u16*)take((size_t)1024 * 1024 * 2);
    u16* dW1abt = (u16*)take((size_t)1024 * 2048 * 2);
    u16* dW2bt  = (u16*)take((size_t)2048 * 1024 * 2);
    u16* Hall   = (u16*)take((size_t)63 * 256 * 2048 * 2);
    int* latidx = (int*)take((size_t)63 * 256 * 32 * 4);
    u16* embR   = (u16*)take((size_t)16384 * 1024 * 2);   // reused as latsum
    u16* enc    = (u16*)take((size_t)16384 * 1024 * 2);
    char* X     = take((size_t)33554432);                  // flat-chunk / d1 / step bufs

    u16* flatc = (u16*)X;                                  // (8192 x 2048) per pass
    u16* d1    = (u16*)X;                                  // (16128 x 1024)
    u16* x_bf  = (u16*)X;                                  // (256 x 1024)
    float* gx  = (float*)(X + 0x100000);                   // (256 x 6144)
    float* gh  = (float*)(X + 0x100000 + 6291456);         // (256 x 6144)
    float* hf32 = (float*)(X + 0x100000 + 2 * 6291456);    // (256 x 2048)
    float* PrPo = (float*)(X + 0x100000 + 2 * 6291456 + 2097152);        // (256 x 2048)
    u16* p1q1 = (u16*)(X + 0x100000 + 2 * 6291456 + 2 * 2097152);        // (256 x 2048)

    k_init<<<1, 1, 0, stream>>>(accum);

    // weight conversion (bf16; all B-matrices stored [N][K])
    k_cast<<<6144, 256, 0, stream>>>(Wih, WihB, 6291456 / 4);
    k_cast<<<12288, 256, 0, stream>>>(Whh, WhhB, 12582912 / 4);
    k_transpose<<<dim3(64, 32), dim3(32, 8), 0, stream>>>(encW, 1024, encWbt, 2048);
    k_transpose<<<dim3(64, 32), dim3(32, 8), 0, stream>>>(tW1, 1024, l1B, 2048);
    k_transpose<<<dim3(64, 32), dim3(32, 8), 0, stream>>>(rW1, 1024, l1B + (size_t)1024 * 2048, 2048);
    k_transpose<<<dim3(32, 32), dim3(32, 8), 0, stream>>>(tW2, 1024, tW2bt, 1024);
    k_transpose<<<dim3(32, 32), dim3(32, 8), 0, stream>>>(rW2, 1024, rW2bt, 1024);
    k_transpose<<<dim3(32, 32), dim3(32, 8), 0, stream>>>(rW1 + (size_t)2048 * 1024, 1024, rW1bbt, 1024);
    k_transpose<<<dim3(64, 32), dim3(32, 8), 0, stream>>>(dW1, 1024, dW1abt, 2048);
    k_transpose<<<dim3(32, 64), dim3(32, 8), 0, stream>>>(dW2, 2048, dW2bt, 1024);

    // phase 1: encoder (2 passes to bound scratch) + embR precompute
    for (int pass = 0; pass < 2; ++pass) {
        k_prep<<<16384, 256, 0, stream>>>(zs + (size_t)pass * 8192 * 2048, zmean, zstd, flatc);
        GP e{}; e.A = flatc; e.lda = 2048; e.Bt = encWbt; e.Cb = enc + (size_t)pass * 8192 * 1024;
        e.ldc = 1024; e.bias = encb; e.K = 2048; e.gridN = 8;
        gemm_k<4, 4, 1, false><<<dim3(512), 256, 0, stream>>>(e, e);
    }
    {
        GP e{}; e.A = enc; e.lda = 1024; e.Bt = rW1bbt; e.Cb = embR; e.ldc = 1024;
        e.bias = rb1; e.K = 1024; e.gridN = 8;
        gemm_k<4, 4, 2, false><<<dim3(1024), 256, 0, stream>>>(e, e);
    }

    // phase 2: sequential scan
    for (int t = 0; t < 63; ++t) {
        GP g0{}; g0.A = x_bf; g0.lda = 1024; g0.Bt = WihB; g0.Cf = gx; g0.ldc = 6144;
        g0.bias = bih; g0.K = 1024; g0.gridN = 48;
        if (t == 0) {
            k_xpre0<<<256, 256, 0, stream>>>(preW, preb, actions, x_bf);
            gemm_k<2, 4, 0, false><<<dim3(192), 256, 0, stream>>>(g0, g0);
            k_gru<true><<<2048, 256, 0, stream>>>(gx, gh, bhh, hf32, hf32, Hall);
        } else {
            GP g1 = g0; g1.A = Hall + (size_t)(t - 1) * 256 * 2048; g1.lda = 2048;
            g1.Bt = WhhB; g1.Cf = gh; g1.bias = bhh; g1.K = 2048;
            gemm_k<2, 4, 0, true><<<dim3(192, 2), 256, 0, stream>>>(g0, g1);
            k_gru<false><<<2048, 256, 0, stream>>>(gx, gh, bhh, hf32, hf32, Hall + (size_t)t * 256 * 2048);
        }
        GP l1{}; l1.A = Hall + (size_t)t * 256 * 2048; l1.lda = 2048; l1.Bt = l1B; l1.Cb = p1q1;
        l1.ldc = 2048; l1.bias = tb1; l1.aux = embR + (size_t)(t + 1) * 1024; l1.auxld = 65536;
        l1.K = 2048; l1.gridN = 32;
        gemm_k<2, 2, 3, false><<<dim3(128), 256, 0, stream>>>(l1, l1);

        GP q0{}; q0.A = p1q1; q0.lda = 2048; q0.Bt = tW2bt; q0.Cf = PrPo; q0.ldc = 2048;
        q0.bias = tb2; q0.K = 1024; q0.gridN = 16;
        GP q1 = q0; q1.A = p1q1 + 1024; q1.Bt = rW2bt; q1.Cf = PrPo + 1024; q1.bias = rb2;
        gemm_k<2, 2, 0, true><<<dim3(64, 2), 256, 0, stream>>>(q0, q1);

        k_smx<<<256, 256, 0, stream>>>(PrPo, latidx + (size_t)t * 256 * 32, accum + 1,
                                       preW, preb, actions, x_bf, t + 1, (t < 62) ? 1 : 0);
    }

    // phase 3: decoder + fused recon
    k_latsum<<<16128, 256, 0, stream>>>(dW1, db1, latidx, embR);
    {
        GP d{}; d.A = Hall; d.lda = 2048; d.Bt = dW1abt; d.Cb = d1; d.ldc = 1024;
        d.aux = embR; d.auxld = 1024; d.K = 2048; d.gridN = 8;
        gemm_k<4, 4, 4, false><<<dim3(1008), 256, 0, stream>>>(d, d);
    }
    {
        GP d{}; d.A = d1; d.lda = 1024; d.Bt = dW2bt; d.ldc = 2048; d.bias = db2;
        d.zs = zs; d.zmean = zmean; d.zstd = zstd; d.accum = accum; d.K = 1024; d.gridN = 16;
        gemm_k<4, 4, 5, false><<<dim3(2016), 256, 0, stream>>>(d, d);
    }
    k_finalize<<<1, 1, 0, stream>>>(accum, (float*)d_out);
}

// Round 2
// 4662.695 us; speedup vs baseline: 1.3267x; 1.3267x over previous
//
#include <hip/hip_runtime.h>
#include <hip/hip_bf16.h>
#include <math.h>

typedef unsigned short u16;
typedef __attribute__((ext_vector_type(8))) short s16x8;
typedef __attribute__((ext_vector_type(4))) short s16x4;
typedef __attribute__((ext_vector_type(4))) float f32x4;

#define DEVI static __device__ __forceinline__

DEVI u16 f2bfu(float f) {
    unsigned u = __float_as_uint(f);
    unsigned r = (u + 0x7fffu + ((u >> 16) & 1u)) >> 16;
    return (u16)r;
}
DEVI float bfu2f(u16 u) { return __uint_as_float(((unsigned)u) << 16); }
DEVI float eluf(float x) { return x > 0.f ? x : (expf(x) - 1.f); }
DEVI float sigm(float x) { return 1.f / (1.f + expf(-x)); }

#define GLOAD16(gsrc, ldst)                                                            \
    __builtin_amdgcn_global_load_lds(                                                  \
        (__attribute__((address_space(1))) void*)(void*)(gsrc),                        \
        (__attribute__((address_space(3))) void*)(ldst), 16, 0, 0)

struct GP {
    const u16* A; int lda;
    const u16* Bt;
    float* Cf; u16* Cb; int ldc;
    const float* bias;
    const u16* aux; int auxld;     // EPI3: embR row (pre-offset); EPI4: latsum
    const float* zs;               // EPI5
    const float* zmean; const float* zstd;
    double* accum;
    int K; int gridN;
};

// ---------------------------------------------------------------------------
// Legacy GEMM (BK=32, 4 waves) — kept byte-identical for encoder/decoder paths
// ---------------------------------------------------------------------------
template <int MF, int NF, int EPI, bool DUAL>
__global__ __launch_bounds__(256) void gemm_k(GP p0, GP p1) {
    GP p = (DUAL && blockIdx.y) ? p1 : p0;
    constexpr int BM = 32 * MF, BN = 32 * NF;
    constexpr int ABYTES = BM * 64, BBYTES = BN * 64;

    const int tid = threadIdx.x;
    const int w = tid >> 6, lane = tid & 63;
    const int bid = blockIdx.x;
    const int bn = bid % p.gridN, bm = bid / p.gridN;
    const int r0 = bm * BM, c0 = bn * BN;
    const int wm = w >> 1, wn = w & 1;

    __shared__ __attribute__((aligned(16))) char sm[2 * (ABYTES + BBYTES)];
    __shared__ float ps[4];

    auto stage = [&](int kt, int buf) {
        char* s = sm + buf * (ABYTES + BBYTES);
        const u16* Ag = p.A + (size_t)r0 * p.lda + kt * 32;
#pragma unroll
        for (int it = 0; it < BM / 64; ++it) {
            int bo = it * 4096 + w * 1024 + lane * 16;
            int row = bo >> 6, kg = (bo & 63) >> 4;
            GLOAD16(Ag + (size_t)row * p.lda + kg * 8, s + bo);
        }
        const u16* Bg = p.Bt + (size_t)c0 * p.K + kt * 32;
        char* sb = s + ABYTES;
#pragma unroll
        for (int it = 0; it < BN / 64; ++it) {
            int bo = it * 4096 + w * 1024 + lane * 16;
            int row = bo >> 6, kg = (bo & 63) >> 4;
            GLOAD16(Bg + (size_t)row * p.K + kg * 8, sb + bo);
        }
    };

    f32x4 acc[MF][NF];
#pragma unroll
    for (int mf = 0; mf < MF; ++mf)
#pragma unroll
        for (int nf = 0; nf < NF; ++nf) acc[mf][nf] = (f32x4){0.f, 0.f, 0.f, 0.f};

    const int nk = p.K >> 5;
    stage(0, 0);
    asm volatile("s_waitcnt vmcnt(0)" ::: "memory");
    __syncthreads();
    int cur = 0;
    for (int kt = 0; kt < nk; ++kt) {
        if (kt + 1 < nk) stage(kt + 1, cur ^ 1);
        const char* s = sm + cur * (ABYTES + BBYTES);
        s16x8 aF[MF], bF[NF];
#pragma unroll
        for (int mf = 0; mf < MF; ++mf)
            aF[mf] = *(const s16x8*)(s + ((wm * MF + mf) * 16 + (lane & 15)) * 64 + (lane >> 4) * 16);
#pragma unroll
        for (int nf = 0; nf < NF; ++nf)
            bF[nf] = *(const s16x8*)(s + ABYTES + ((wn * NF + nf) * 16 + (lane & 15)) * 64 + (lane >> 4) * 16);
#pragma unroll
        for (int mf = 0; mf < MF; ++mf)
#pragma unroll
            for (int nf = 0; nf < NF; ++nf)
                acc[mf][nf] = __builtin_amdgcn_mfma_f32_16x16x32_bf16(aF[mf], bF[nf], acc[mf][nf], 0, 0, 0);
        asm volatile("s_waitcnt vmcnt(0)" ::: "memory");
        __syncthreads();
        cur ^= 1;
    }

    const int lrow4 = (lane >> 4) << 2, lcol = lane & 15;
    float lsum = 0.f;
#pragma unroll
    for (int mf = 0; mf < MF; ++mf) {
        int rowb = r0 + (wm * MF + mf) * 16 + lrow4;
#pragma unroll
        for (int nf = 0; nf < NF; ++nf) {
            int col = c0 + (wn * NF + nf) * 16 + lcol;
#pragma unroll
            for (int j = 0; j < 4; ++j) {
                float v = acc[mf][nf][j];
                int r = rowb + j;
                if constexpr (EPI == 0) {
                    p.Cf[(size_t)r * p.ldc + col] = v + p.bias[col];
                } else if constexpr (EPI == 1) {
                    p.Cb[(size_t)r * p.ldc + col] = f2bfu(eluf(v + p.bias[col]));
                } else if constexpr (EPI == 2) {
                    p.Cb[(size_t)r * p.ldc + col] = f2bfu(v + p.bias[col]);
                } else if constexpr (EPI == 4) {
                    p.Cb[(size_t)r * p.ldc + col] = f2bfu(eluf(v + bfu2f(p.aux[(size_t)r * p.auxld + col])));
                } else if constexpr (EPI == 5) {
                    v += p.bias[col];
                    int tt = r >> 8, b = r & 255;
                    int ch = col >> 9;
                    float z = (p.zs[((size_t)b * 64 + tt + 1) * 2048 + col] - p.zmean[ch]) / p.zstd[ch];
                    float d = v - z;
                    lsum += d * d;
                }
            }
        }
    }
    if constexpr (EPI == 5) {
#pragma unroll
        for (int o = 32; o > 0; o >>= 1) lsum += __shfl_down(lsum, o, 64);
        if (lane == 0) ps[w] = lsum;
        __syncthreads();
        if (tid == 0) {
            double s = (double)ps[0] + (double)ps[1] + (double)ps[2] + (double)ps[3];
            atomicAdd(p.accum, s);
        }
    }
}

// ---------------------------------------------------------------------------
// New swizzled GEMM (BK=64, T2 XOR-swizzle, templated wave grid, dual-problem)
// ---------------------------------------------------------------------------
template <int EPI, int MF, int NF>
DEVI void epiS(const GP& p, f32x4 (&acc)[MF][NF], int r0, int c0, int wm, int wn,
               int lrow4, int lcol) {
#pragma unroll
    for (int mf = 0; mf < MF; ++mf) {
        int rowb = r0 + (wm * MF + mf) * 16 + lrow4;
#pragma unroll
        for (int nf = 0; nf < NF; ++nf) {
            int col = c0 + (wn * NF + nf) * 16 + lcol;
#pragma unroll
            for (int j = 0; j < 4; ++j) {
                float v = acc[mf][nf][j];
                int r = rowb + j;
                if constexpr (EPI == 0) {
                    p.Cf[(size_t)r * p.ldc + col] = v + p.bias[col];
                } else if constexpr (EPI == 3) {
                    float t;
                    if (col < 1024) t = eluf(v + p.bias[col]);
                    else t = eluf(v + bfu2f(p.aux[(size_t)r * p.auxld + (col - 1024)]));
                    p.Cb[(size_t)r * p.ldc + col] = f2bfu(t);
                }
            }
        }
    }
}

template <int WM, int WN, int MF, int NF, int EPIa, int EPIb>
__global__ __launch_bounds__(WM * WN * 64) void gemmS(GP pa, GP pb, int nA) {
    constexpr int NT = WM * WN * 64;
    constexpr int BM = WM * MF * 16, BN = WN * NF * 16;
    constexpr int ABY = BM * 128, BBY = BN * 128;

    const int tid = threadIdx.x, w = tid >> 6, lane = tid & 63;
    const bool isA = (int)blockIdx.x < nA;
    GP p = isA ? pa : pb;
    const int bid = isA ? blockIdx.x : blockIdx.x - nA;
    const int bn = bid % p.gridN, bm = bid / p.gridN;
    const int r0 = bm * BM, c0 = bn * BN;
    const int wm = w / WN, wn = w % WN;

    __shared__ __attribute__((aligned(16))) char sm[2 * (ABY + BBY)];

    auto stage = [&](int kt, int buf) {
        char* s = sm + buf * (ABY + BBY);
#pragma unroll
        for (int it = 0; it < ABY / (NT * 16); ++it) {
            int bo = it * (NT * 16) + tid * 16;
            int row = bo >> 7, kb = bo & 127;
            int kbs = kb ^ ((row & 7) << 4);                       // pre-swizzled source
            GLOAD16(p.A + (size_t)(r0 + row) * p.lda + kt * 64 + (kbs >> 1), s + bo);
        }
        char* sb = s + ABY;
#pragma unroll
        for (int it = 0; it < BBY / (NT * 16); ++it) {
            int bo = it * (NT * 16) + tid * 16;
            int row = bo >> 7, kb = bo & 127;
            int kbs = kb ^ ((row & 7) << 4);
            GLOAD16(p.Bt + (size_t)(c0 + row) * p.K + kt * 64 + (kbs >> 1), sb + bo);
        }
    };

    f32x4 acc[MF][NF];
#pragma unroll
    for (int mf = 0; mf < MF; ++mf)
#pragma unroll
        for (int nf = 0; nf < NF; ++nf) acc[mf][nf] = (f32x4){0.f, 0.f, 0.f, 0.f};

    const int nk = p.K >> 6;
    stage(0, 0);
    asm volatile("s_waitcnt vmcnt(0)" ::: "memory");
    __syncthreads();
    int cur = 0;
    for (int kt = 0; kt < nk; ++kt) {
        if (kt + 1 < nk) stage(kt + 1, cur ^ 1);
        const char* s = sm + cur * (ABY + BBY);
#pragma unroll
        for (int ks = 0; ks < 2; ++ks) {
            const int kb = ks * 64 + ((lane >> 4) << 4);
            s16x8 aF[MF], bF[NF];
#pragma unroll
            for (int mf = 0; mf < MF; ++mf) {
                int rt = (wm * MF + mf) * 16 + (lane & 15);
                aF[mf] = *(const s16x8*)(s + rt * 128 + (kb ^ ((rt & 7) << 4)));
            }
#pragma unroll
            for (int nf = 0; nf < NF; ++nf) {
                int rt = (wn * NF + nf) * 16 + (lane & 15);
                bF[nf] = *(const s16x8*)(s + ABY + rt * 128 + (kb ^ ((rt & 7) << 4)));
            }
#pragma unroll
            for (int mf = 0; mf < MF; ++mf)
#pragma unroll
                for (int nf = 0; nf < NF; ++nf)
                    acc[mf][nf] = __builtin_amdgcn_mfma_f32_16x16x32_bf16(aF[mf], bF[nf], acc[mf][nf], 0, 0, 0);
        }
        asm volatile("s_waitcnt vmcnt(0)" ::: "memory");
        __syncthreads();
        cur ^= 1;
    }

    const int lrow4 = (lane >> 4) << 2, lcol = lane & 15;
    if (isA) epiS<EPIa, MF, NF>(p, acc, r0, c0, wm, wn, lrow4, lcol);
    else     epiS<EPIb, MF, NF>(p, acc, r0, c0, wm, wn, lrow4, lcol);
}

// ---------------------------------------------------------------------------
// k_gates: gx (K=1024, 3 gate tiles) + full GRU epilogue (reads precomputed GH)
// Grid 256 blocks: bm=bid>>6 (rows 64), bn=bid&63 (h-cols 32). 4 waves 2x2.
// ---------------------------------------------------------------------------
template <bool FIRST>
__global__ __launch_bounds__(256) void k_gates(const u16* __restrict__ X, const u16* __restrict__ WihB,
                                               const float* __restrict__ bih, const float* __restrict__ bhh,
                                               const float* __restrict__ GH, float* __restrict__ hf32,
                                               u16* __restrict__ hallT) {
    constexpr int ABY = 64 * 128;       // 8 KB
    constexpr int BTB = 32 * 128;       // 4 KB per gate tile
    const int tid = threadIdx.x, w = tid >> 6, lane = tid & 63;
    const int bm = blockIdx.x >> 6, bn = blockIdx.x & 63;
    const int r0 = bm * 64, c0 = bn * 32;
    const int wm = w >> 1, wn = w & 1;

    __shared__ __attribute__((aligned(16))) char sm[2 * (ABY + 3 * BTB)];

    auto stage = [&](int kt, int buf) {
        char* s = sm + buf * (ABY + 3 * BTB);
#pragma unroll
        for (int it = 0; it < 2; ++it) {
            int bo = it * 4096 + tid * 16;
            int row = bo >> 7, kb = bo & 127;
            int kbs = kb ^ ((row & 7) << 4);
            GLOAD16(X + (size_t)(r0 + row) * 1024 + kt * 64 + (kbs >> 1), s + bo);
        }
        char* sb = s + ABY;
#pragma unroll
        for (int g = 0; g < 3; ++g) {
            int bo = tid * 16;
            int row = bo >> 7, kb = bo & 127;
            int kbs = kb ^ ((row & 7) << 4);
            GLOAD16(WihB + (size_t)(g * 2048 + c0 + row) * 1024 + kt * 64 + (kbs >> 1), sb + g * BTB + bo);
        }
    };

    f32x4 acc[3][2];
#pragma unroll
    for (int g = 0; g < 3; ++g)
#pragma unroll
        for (int mf = 0; mf < 2; ++mf) acc[g][mf] = (f32x4){0.f, 0.f, 0.f, 0.f};

    stage(0, 0);
    asm volatile("s_waitcnt vmcnt(0)" ::: "memory");
    __syncthreads();
    int cur = 0;
    for (int kt = 0; kt < 16; ++kt) {
        if (kt < 15) stage(kt + 1, cur ^ 1);
        const char* s = sm + cur * (ABY + 3 * BTB);
#pragma unroll
        for (int ks = 0; ks < 2; ++ks) {
            const int kb = ks * 64 + ((lane >> 4) << 4);
            s16x8 aF[2], bF[3];
#pragma unroll
            for (int mf = 0; mf < 2; ++mf) {
                int rt = (wm * 2 + mf) * 16 + (lane & 15);
                aF[mf] = *(const s16x8*)(s + rt * 128 + (kb ^ ((rt & 7) << 4)));
            }
#pragma unroll
            for (int g = 0; g < 3; ++g) {
                int rt = wn * 16 + (lane & 15);
                bF[g] = *(const s16x8*)(s + ABY + g * BTB + rt * 128 + (kb ^ ((rt & 7) << 4)));
            }
#pragma unroll
            for (int g = 0; g < 3; ++g)
#pragma unroll
                for (int mf = 0; mf < 2; ++mf)
                    acc[g][mf] = __builtin_amdgcn_mfma_f32_16x16x32_bf16(aF[mf], bF[g], acc[g][mf], 0, 0, 0);
        }
        asm volatile("s_waitcnt vmcnt(0)" ::: "memory");
        __syncthreads();
        cur ^= 1;
    }

    const int lrow4 = (lane >> 4) << 2, lcol = lane & 15;
    const int cc = c0 + wn * 16 + lcol;
#pragma unroll
    for (int mf = 0; mf < 2; ++mf) {
        int rr0 = r0 + (wm * 2 + mf) * 16 + lrow4;
#pragma unroll
        for (int j = 0; j < 4; ++j) {
            int rr = rr0 + j;
            float xr = acc[0][mf][j] + bih[cc];
            float xz = acc[1][mf][j] + bih[2048 + cc];
            float xn = acc[2][mf][j] + bih[4096 + cc];
            float hr_, hz_, hn_;
            if (FIRST) { hr_ = bhh[cc]; hz_ = bhh[2048 + cc]; hn_ = bhh[4096 + cc]; }
            else {
                const float* g = GH + (size_t)rr * 6144;
                hr_ = g[cc]; hz_ = g[2048 + cc]; hn_ = g[4096 + cc];
            }
            float r = sigm(xr + hr_);
            float u = sigm(xz + hz_);
            float n = tanhf(xn + r * hn_);
            float hold = FIRST ? 0.f : hf32[(size_t)rr * 2048 + cc];
            float h = (1.f - u) * n + u * hold;
            hf32[(size_t)rr * 2048 + cc] = h;
            hallT[(size_t)rr * 2048 + cc] = f2bfu(h);
        }
    }
}

// ---------------------------------------------------------------------------
// small kernels
// ---------------------------------------------------------------------------
__global__ void k_init(double* acc) { acc[0] = 0.0; acc[1] = 0.0; }

__global__ void k_cast(const float* __restrict__ src, u16* __restrict__ dst, int n4) {
    int i = blockIdx.x * 256 + threadIdx.x;
    if (i >= n4) return;
    f32x4 v = *(const f32x4*)(src + (size_t)i * 4);
    s16x4 o;
    o[0] = (short)f2bfu(v[0]); o[1] = (short)f2bfu(v[1]);
    o[2] = (short)f2bfu(v[2]); o[3] = (short)f2bfu(v[3]);
    *(s16x4*)(dst + (size_t)i * 4) = o;
}

__global__ void k_transpose(const float* __restrict__ src, int sld, u16* __restrict__ dst, int K) {
    __shared__ float tile[32][33];
    int k0 = blockIdx.x * 32, n0 = blockIdx.y * 32;
    for (int r = threadIdx.y; r < 32; r += 8)
        tile[r][threadIdx.x] = src[(size_t)(k0 + r) * sld + n0 + threadIdx.x];
    __syncthreads();
    for (int r = threadIdx.y; r < 32; r += 8)
        dst[(size_t)(n0 + r) * K + k0 + threadIdx.x] = f2bfu(tile[threadIdx.x][r]);
}

__global__ void k_prep(const float* __restrict__ zsp, const float* __restrict__ zm,
                       const float* __restrict__ zsd, u16* __restrict__ flat) {
    size_t i = ((size_t)blockIdx.x * 256 + threadIdx.x) * 4;
    f32x4 v = *(const f32x4*)(zsp + i);
    int ch = ((int)(i >> 9)) & 3;
    float m = zm[ch], s = zsd[ch];
    s16x4 o;
    o[0] = (short)f2bfu((v[0] - m) / s); o[1] = (short)f2bfu((v[1] - m) / s);
    o[2] = (short)f2bfu((v[2] - m) / s); o[3] = (short)f2bfu((v[3] - m) / s);
    *(s16x4*)(flat + i) = o;
}

__global__ __launch_bounds__(256) void k_xpre0(const float* __restrict__ preW, const float* __restrict__ preb,
                                               const float* __restrict__ actions, u16* __restrict__ xout) {
    int b = blockIdx.x, tid = threadIdx.x;
    __shared__ float as[3];
    if (tid < 3) as[tid] = actions[(size_t)b * 64 * 3 + tid];
    __syncthreads();
    for (int j = tid; j < 1024; j += 256) {
        float s = preb[j] + as[0] * preW[1024 * 1024 + j] + as[1] * preW[1025 * 1024 + j] + as[2] * preW[1026 * 1024 + j];
        xout[(b << 10) + j] = f2bfu(eluf(s));
    }
}

// softmax/argmax/KL per batch row + fused pre-MLP x for next step (bf16 gather)
__global__ __launch_bounds__(256) void k_smx(const float* __restrict__ PrPo, int* __restrict__ latidx_t,
                                             double* __restrict__ klacc,
                                             const u16* __restrict__ PreLatB, const float* __restrict__ preW,
                                             const float* __restrict__ preb,
                                             const float* __restrict__ actions, u16* __restrict__ xout,
                                             int tnext, int do_x) {
    int b = blockIdx.x, tid = threadIdx.x;
    const float* Pr = PrPo + (size_t)b * 2048;
    const float* Po = Pr + 1024;
    __shared__ float klpart[32];
    __shared__ int idxs[32];
    __shared__ float as[3];
    int grp = tid >> 5, c = tid & 31;
#pragma unroll
    for (int it = 0; it < 4; ++it) {
        int l = it * 8 + grp;
        float po = Po[l * 32 + c];
        float pr = Pr[l * 32 + c];
        float mv = po; int mi = c;
#pragma unroll
        for (int o = 16; o > 0; o >>= 1) {
            float ov = __shfl_xor(mv, o, 32);
            int oi = __shfl_xor(mi, o, 32);
            if (ov > mv || (ov == mv && oi < mi)) { mv = ov; mi = oi; }
        }
        float mq = pr;
#pragma unroll
        for (int o = 16; o > 0; o >>= 1) mq = fmaxf(mq, __shfl_xor(mq, o, 32));
        float ep = expf(po - mv), eq = expf(pr - mq);
        float sp = ep, sq = eq;
#pragma unroll
        for (int o = 16; o > 0; o >>= 1) { sp += __shfl_xor(sp, o, 32); sq += __shfl_xor(sq, o, 32); }
        float logp = po - mv - logf(sp);
        float logq = pr - mq - logf(sq);
        float klc = (ep / sp) * (logp - logq);
#pragma unroll
        for (int o = 16; o > 0; o >>= 1) klc += __shfl_xor(klc, o, 32);
        if (c == 0) { klpart[l] = klc; idxs[l] = mi; }
    }
    __syncthreads();
    if (tid == 0) {
        float kl = 0.f;
        for (int l = 0; l < 32; ++l) kl += klpart[l];
        atomicAdd(klacc, (double)fmaxf(kl, 1.0f));
    }
    if (tid < 32) latidx_t[(b << 5) + tid] = idxs[tid];
    if (do_x) {
        if (tid < 3) as[tid] = actions[((size_t)b * 64 + tnext) * 3 + tid];
        __syncthreads();
        const int j4 = tid * 4;
        f32x4 s = *(const f32x4*)(preb + j4);
#pragma unroll
        for (int cc = 0; cc < 3; ++cc) {
            f32x4 wv = *(const f32x4*)(preW + (size_t)(1024 + cc) * 1024 + j4);
            s[0] += as[cc] * wv[0]; s[1] += as[cc] * wv[1];
            s[2] += as[cc] * wv[2]; s[3] += as[cc] * wv[3];
        }
#pragma unroll
        for (int l = 0; l < 32; ++l) {
            s16x4 v = *(const s16x4*)(PreLatB + (size_t)((l << 5) + idxs[l]) * 1024 + j4);
            s[0] += bfu2f((u16)v[0]); s[1] += bfu2f((u16)v[1]);
            s[2] += bfu2f((u16)v[2]); s[3] += bfu2f((u16)v[3]);
        }
        s16x4 o;
        o[0] = (short)f2bfu(eluf(s[0])); o[1] = (short)f2bfu(eluf(s[1]));
        o[2] = (short)f2bfu(eluf(s[2])); o[3] = (short)f2bfu(eluf(s[3]));
        *(s16x4*)(xout + (b << 10) + j4) = o;
    }
}

// latsum[m][j] = db1[j] + sum_l LatB[l*32+idx][j]   (bf16 gather, vectorized)
__global__ __launch_bounds__(256) void k_latsum(const u16* __restrict__ LatB, const float* __restrict__ db1,
                                                const int* __restrict__ latidx_all, u16* __restrict__ latsum) {
    int m = blockIdx.x, tid = threadIdx.x;
    __shared__ int idxs[32];
    if (tid < 32) idxs[tid] = latidx_all[(size_t)m * 32 + tid];
    __syncthreads();
    const int j4 = tid * 4;
    f32x4 s = *(const f32x4*)(db1 + j4);
#pragma unroll
    for (int l = 0; l < 32; ++l) {
        s16x4 v = *(const s16x4*)(LatB + (size_t)((l << 5) + idxs[l]) * 1024 + j4);
        s[0] += bfu2f((u16)v[0]); s[1] += bfu2f((u16)v[1]);
        s[2] += bfu2f((u16)v[2]); s[3] += bfu2f((u16)v[3]);
    }
    s16x4 o;
    o[0] = (short)f2bfu(s[0]); o[1] = (short)f2bfu(s[1]);
    o[2] = (short)f2bfu(s[2]); o[3] = (short)f2bfu(s[3]);
    *(s16x4*)(latsum + (size_t)m * 1024 + j4) = o;
}

__global__ void k_finalize(const double* acc, float* out) {
    out[0] = (float)(acc[0] / 33030144.0 + acc[1] / 16128.0);
}

// ---------------------------------------------------------------------------
extern "C" void kernel_launch(void* const* d_in, const int* in_sizes, int n_in,
                              void* d_out, int out_size, void* d_ws, size_t ws_size,
                              hipStream_t stream) {
    const float* zs      = (const float*)d_in[0];
    const float* actions = (const float*)d_in[1];
    const float* zmean   = (const float*)d_in[2];
    const float* zstd    = (const float*)d_in[3];
    const float* encW    = (const float*)d_in[4];
    const float* encb    = (const float*)d_in[5];
    const float* preW    = (const float*)d_in[6];
    const float* preb    = (const float*)d_in[7];
    const float* Wih     = (const float*)d_in[8];
    const float* Whh     = (const float*)d_in[9];
    const float* bih     = (const float*)d_in[10];
    const float* bhh     = (const float*)d_in[11];
    const float* tW1     = (const float*)d_in[12];
    const float* tb1     = (const float*)d_in[13];
    const float* tW2     = (const float*)d_in[14];
    const float* tb2     = (const float*)d_in[15];
    const float* rW1     = (const float*)d_in[16];
    const float* rb1     = (const float*)d_in[17];
    const float* rW2     = (const float*)d_in[18];
    const float* rb2     = (const float*)d_in[19];
    const float* dW1     = (const float*)d_in[20];
    const float* db1     = (const float*)d_in[21];
    const float* dW2     = (const float*)d_in[22];
    const float* db2     = (const float*)d_in[23];

    char* W = (char*)d_ws;
    size_t off = 0;
    auto take = [&](size_t b) { char* p = W + off; off += (b + 255) & ~(size_t)255; return p; };

    double* accum  = (double*)take(16);
    u16* encWbt = (u16*)take((size_t)1024 * 2048 * 2);
    u16* WihB   = (u16*)take((size_t)6144 * 1024 * 2);
    u16* WhhB   = (u16*)take((size_t)6144 * 2048 * 2);
    u16* l1B    = (u16*)take((size_t)2048 * 2048 * 2);
    u16* tW2bt  = (u16*)take((size_t)1024 * 1024 * 2);
    u16* rW2bt  = (u16*)take((size_t)1024 * 1024 * 2);
    u16* rW1bbt = (u16*)take((size_t)1024 * 1024 * 2);
    u16* dW1abt = (u16*)take((size_t)1024 * 2048 * 2);
    u16* dW2bt  = (u16*)take((size_t)2048 * 1024 * 2);
    u16* PreLatB = (u16*)take((size_t)1024 * 1024 * 2);
    u16* LatB    = (u16*)take((size_t)1024 * 1024 * 2);
    u16* Hall   = (u16*)take((size_t)63 * 256 * 2048 * 2);
    int* latidx = (int*)take((size_t)63 * 256 * 32 * 4);
    u16* embR   = (u16*)take((size_t)16384 * 1024 * 2);   // reused as latsum in phase 3
    u16* enc    = (u16*)take((size_t)16384 * 1024 * 2);
    float* GH   = (float*)take((size_t)2 * 256 * 6144 * 4);
    float* hf32 = (float*)take((size_t)256 * 2048 * 4);
    u16* x_bf   = (u16*)take((size_t)256 * 1024 * 2);
    float* PrPo = (float*)take((size_t)256 * 2048 * 4);
    u16* p1q1   = (u16*)take((size_t)256 * 2048 * 2);
    char* X     = take((size_t)34000000);                 // flatc / d1 shared scratch

    u16* flatc = (u16*)X;                                  // (8192 x 2048) per pass
    u16* d1    = (u16*)X;                                  // (16128 x 1024)

    k_init<<<1, 1, 0, stream>>>(accum);

    // weight conversion
    k_cast<<<6144, 256, 0, stream>>>(Wih, WihB, 6291456 / 4);
    k_cast<<<12288, 256, 0, stream>>>(Whh, WhhB, 12582912 / 4);
    k_cast<<<1024, 256, 0, stream>>>(preW, PreLatB, 262144);
    k_cast<<<1024, 256, 0, stream>>>(dW1 + (size_t)2048 * 1024, LatB, 262144);
    k_transpose<<<dim3(64, 32), dim3(32, 8), 0, stream>>>(encW, 1024, encWbt, 2048);
    k_transpose<<<dim3(64, 32), dim3(32, 8), 0, stream>>>(tW1, 1024, l1B, 2048);
    k_transpose<<<dim3(64, 32), dim3(32, 8), 0, stream>>>(rW1, 1024, l1B + (size_t)1024 * 2048, 2048);
    k_transpose<<<dim3(32, 32), dim3(32, 8), 0, stream>>>(tW2, 1024, tW2bt, 1024);
    k_transpose<<<dim3(32, 32), dim3(32, 8), 0, stream>>>(rW2, 1024, rW2bt, 1024);
    k_transpose<<<dim3(32, 32), dim3(32, 8), 0, stream>>>(rW1 + (size_t)2048 * 1024, 1024, rW1bbt, 1024);
    k_transpose<<<dim3(64, 32), dim3(32, 8), 0, stream>>>(dW1, 1024, dW1abt, 2048);
    k_transpose<<<dim3(32, 64), dim3(32, 8), 0, stream>>>(dW2, 2048, dW2bt, 1024);

    // phase 1: encoder (2 passes) + embR precompute
    for (int pass = 0; pass < 2; ++pass) {
        k_prep<<<16384, 256, 0, stream>>>(zs + (size_t)pass * 8192 * 2048, zmean, zstd, flatc);
        GP e{}; e.A = flatc; e.lda = 2048; e.Bt = encWbt; e.Cb = enc + (size_t)pass * 8192 * 1024;
        e.ldc = 1024; e.bias = encb; e.K = 2048; e.gridN = 8;
        gemm_k<4, 4, 1, false><<<dim3(512), 256, 0, stream>>>(e, e);
    }
    {
        GP e{}; e.A = enc; e.lda = 1024; e.Bt = rW1bbt; e.Cb = embR; e.ldc = 1024;
        e.bias = rb1; e.K = 1024; e.gridN = 8;
        gemm_k<4, 4, 2, false><<<dim3(1024), 256, 0, stream>>>(e, e);
    }

    // phase 2: sequential scan (gh-ahead schedule; 4 launches/step)
    k_xpre0<<<256, 256, 0, stream>>>(preW, preb, actions, x_bf);
    for (int t = 0; t < 63; ++t) {
        // k1: gx + GRU (h_t)
        if (t == 0)
            k_gates<true><<<256, 256, 0, stream>>>(x_bf, WihB, bih, bhh, GH, hf32, Hall);
        else
            k_gates<false><<<256, 256, 0, stream>>>(x_bf, WihB, bih, bhh, GH + (size_t)(t & 1) * 256 * 6144,
                                                    hf32, Hall + (size_t)t * 256 * 2048);
        // k2: gh(t+1) || l1(t)
        {
            GP pa{}; pa.A = Hall + (size_t)t * 256 * 2048; pa.lda = 2048; pa.Bt = WhhB;
            pa.Cf = GH + (size_t)((t + 1) & 1) * 256 * 6144; pa.ldc = 6144; pa.bias = bhh;
            pa.K = 2048; pa.gridN = 96;
            GP pb{}; pb.A = Hall + (size_t)t * 256 * 2048; pb.lda = 2048; pb.Bt = l1B; pb.Cb = p1q1;
            pb.ldc = 2048; pb.bias = tb1; pb.aux = embR + (size_t)(t + 1) * 1024; pb.auxld = 65536;
            pb.K = 2048; pb.gridN = 32;
            int nA = (t < 62) ? 192 : 0;
            gemmS<4, 2, 2, 2, 0, 3><<<dim3(nA + 64), 512, 0, stream>>>(pa, pb, nA);
        }
        // k3: q dual (prior/post second layer)
        {
            GP qa{}; qa.A = p1q1; qa.lda = 2048; qa.Bt = tW2bt; qa.Cf = PrPo; qa.ldc = 2048;
            qa.bias = tb2; qa.K = 1024; qa.gridN = 16;
            GP qb = qa; qb.A = p1q1 + 1024; qb.Bt = rW2bt; qb.Cf = PrPo + 1024; qb.bias = rb2;
            gemmS<2, 2, 2, 2, 0, 0><<<dim3(128), 256, 0, stream>>>(qa, qb, 64);
        }
        // k4: softmax/argmax/KL + next x
        k_smx<<<256, 256, 0, stream>>>(PrPo, latidx + (size_t)t * 256 * 32, accum + 1,
                                       PreLatB, preW, preb, actions, x_bf, t + 1, (t < 62) ? 1 : 0);
    }

    // phase 3: decoder + fused recon
    k_latsum<<<16128, 256, 0, stream>>>(LatB, db1, latidx, embR);
    {
        GP d{}; d.A = Hall; d.lda = 2048; d.Bt = dW1abt; d.Cb = d1; d.ldc = 1024;
        d.aux = embR; d.auxld = 1024; d.K = 2048; d.gridN = 8;
        gemm_k<4, 4, 4, false><<<dim3(1008), 256, 0, stream>>>(d, d);
    }
    {
        GP d{}; d.A = d1; d.lda = 1024; d.Bt = dW2bt; d.ldc = 2048; d.bias = db2;
        d.zs = zs; d.zmean = zmean; d.zstd = zstd; d.accum = accum; d.K = 1024; d.gridN = 16;
        gemm_k<4, 4, 5, false><<<dim3(2016), 256, 0, stream>>>(d, d);
    }
    k_finalize<<<1, 1, 0, stream>>>(accum, (float*)d_out);
}

// Round 6
// 4387.082 us; speedup vs baseline: 1.4100x; 1.0628x over previous
//
#include <hip/hip_runtime.h>
#include <hip/hip_bf16.h>
#include <math.h>

typedef unsigned short u16;
typedef __attribute__((ext_vector_type(8))) short s16x8;
typedef __attribute__((ext_vector_type(4))) short s16x4;
typedef __attribute__((ext_vector_type(4))) float f32x4;

#define DEVI static __device__ __forceinline__

DEVI u16 f2bfu(float f) {
    unsigned u = __float_as_uint(f);
    unsigned r = (u + 0x7fffu + ((u >> 16) & 1u)) >> 16;
    return (u16)r;
}
DEVI float bfu2f(u16 u) { return __uint_as_float(((unsigned)u) << 16); }
DEVI float eluf(float x) { return x > 0.f ? x : (expf(x) - 1.f); }
DEVI float sigm(float x) { return 1.f / (1.f + expf(-x)); }

#define GLOAD16(gsrc, ldst)                                                            \
    __builtin_amdgcn_global_load_lds(                                                  \
        (__attribute__((address_space(1))) void*)(void*)(gsrc),                        \
        (__attribute__((address_space(3))) void*)(ldst), 16, 0, 0)

struct GP {
    const u16* A; int lda;
    const u16* Bt;
    float* Cf; u16* Cb; int ldc;
    const float* bias;
    const u16* aux; int auxld;
    const float* zs;               // EPI5
    const float* zmean; const float* zstd;
    double* accum;
    int K; int gridN; int rbase;
};

// ---------------------------------------------------------------------------
// Legacy GEMM (BK=32, 4 waves, 2-phase) — encoder / priors / decoder
// ---------------------------------------------------------------------------
template <int MF, int NF, int EPI, bool DUAL>
__global__ __launch_bounds__(256) void gemm_k(GP p0, GP p1) {
    GP p = (DUAL && blockIdx.y) ? p1 : p0;
    constexpr int BM = 32 * MF, BN = 32 * NF;
    constexpr int ABYTES = BM * 64, BBYTES = BN * 64;

    const int tid = threadIdx.x;
    const int w = tid >> 6, lane = tid & 63;
    const int bid = blockIdx.x;
    const int bn = bid % p.gridN, bm = bid / p.gridN;
    const int r0 = bm * BM, c0 = bn * BN;
    const int wm = w >> 1, wn = w & 1;

    __shared__ __attribute__((aligned(16))) char sm[2 * (ABYTES + BBYTES)];
    __shared__ float ps[4];

    auto stage = [&](int kt, int buf) {
        char* s = sm + buf * (ABYTES + BBYTES);
        const u16* Ag = p.A + (size_t)r0 * p.lda + kt * 32;
#pragma unroll
        for (int it = 0; it < BM / 64; ++it) {
            int bo = it * 4096 + w * 1024 + lane * 16;
            int row = bo >> 6, kg = (bo & 63) >> 4;
            GLOAD16(Ag + (size_t)row * p.lda + kg * 8, s + bo);
        }
        const u16* Bg = p.Bt + (size_t)c0 * p.K + kt * 32;
        char* sb = s + ABYTES;
#pragma unroll
        for (int it = 0; it < BN / 64; ++it) {
            int bo = it * 4096 + w * 1024 + lane * 16;
            int row = bo >> 6, kg = (bo & 63) >> 4;
            GLOAD16(Bg + (size_t)row * p.K + kg * 8, sb + bo);
        }
    };

    f32x4 acc[MF][NF];
#pragma unroll
    for (int mf = 0; mf < MF; ++mf)
#pragma unroll
        for (int nf = 0; nf < NF; ++nf) acc[mf][nf] = (f32x4){0.f, 0.f, 0.f, 0.f};

    const int nk = p.K >> 5;
    stage(0, 0);
    asm volatile("s_waitcnt vmcnt(0)" ::: "memory");
    __syncthreads();
    int cur = 0;
    for (int kt = 0; kt < nk; ++kt) {
        if (kt + 1 < nk) stage(kt + 1, cur ^ 1);
        const char* s = sm + cur * (ABYTES + BBYTES);
        s16x8 aF[MF], bF[NF];
#pragma unroll
        for (int mf = 0; mf < MF; ++mf)
            aF[mf] = *(const s16x8*)(s + ((wm * MF + mf) * 16 + (lane & 15)) * 64 + (lane >> 4) * 16);
#pragma unroll
        for (int nf = 0; nf < NF; ++nf)
            bF[nf] = *(const s16x8*)(s + ABYTES + ((wn * NF + nf) * 16 + (lane & 15)) * 64 + (lane >> 4) * 16);
#pragma unroll
        for (int mf = 0; mf < MF; ++mf)
#pragma unroll
            for (int nf = 0; nf < NF; ++nf)
                acc[mf][nf] = __builtin_amdgcn_mfma_f32_16x16x32_bf16(aF[mf], bF[nf], acc[mf][nf], 0, 0, 0);
        asm volatile("s_waitcnt vmcnt(0)" ::: "memory");
        __syncthreads();
        cur ^= 1;
    }

    const int lrow4 = (lane >> 4) << 2, lcol = lane & 15;
    float lsum = 0.f;
#pragma unroll
    for (int mf = 0; mf < MF; ++mf) {
        int rowb = r0 + (wm * MF + mf) * 16 + lrow4;
#pragma unroll
        for (int nf = 0; nf < NF; ++nf) {
            int col = c0 + (wn * NF + nf) * 16 + lcol;
#pragma unroll
            for (int j = 0; j < 4; ++j) {
                float v = acc[mf][nf][j];
                int r = rowb + j;
                if constexpr (EPI == 1) {
                    p.Cb[(size_t)r * p.ldc + col] = f2bfu(eluf(v + p.bias[col]));
                } else if constexpr (EPI == 2) {
                    p.Cb[(size_t)r * p.ldc + col] = f2bfu(v + p.bias[col]);
                } else if constexpr (EPI == 4) {
                    p.Cb[(size_t)r * p.ldc + col] = f2bfu(eluf(v + bfu2f(p.aux[(size_t)r * p.auxld + col])));
                } else if constexpr (EPI == 5) {
                    v += p.bias[col];
                    int R = r + p.rbase;
                    int tt = R >> 8, b = R & 255;
                    int ch = col >> 9;
                    float z = (p.zs[((size_t)b * 64 + tt + 1) * 2048 + col] - p.zmean[ch]) / p.zstd[ch];
                    float d = v - z;
                    lsum += d * d;
                }
            }
        }
    }
    if constexpr (EPI == 5) {
#pragma unroll
        for (int o = 32; o > 0; o >>= 1) lsum += __shfl_down(lsum, o, 64);
        if (lane == 0) ps[w] = lsum;
        __syncthreads();
        if (tid == 0) {
            double s = (double)ps[0] + (double)ps[1] + (double)ps[2] + (double)ps[3];
            atomicAdd(p.accum, s);
        }
    }
}

// ---------------------------------------------------------------------------
// Scan GEMM: BK=64, T2 XOR-swizzle, PROVEN 2-buffer vmcnt(0)+__syncthreads loop
// ---------------------------------------------------------------------------
template <int EPI, int MF, int NF>
DEVI void epiS(const GP& p, f32x4 (&acc)[MF][NF], int r0, int c0, int wm, int wn,
               int lrow4, int lcol) {
#pragma unroll
    for (int mf = 0; mf < MF; ++mf) {
        int rowb = r0 + (wm * MF + mf) * 16 + lrow4;
#pragma unroll
        for (int nf = 0; nf < NF; ++nf) {
            int col = c0 + (wn * NF + nf) * 16 + lcol;
#pragma unroll
            for (int j = 0; j < 4; ++j) {
                float v = acc[mf][nf][j];
                int r = rowb + j;
                if constexpr (EPI == 4) {
                    p.Cb[(size_t)r * p.ldc + col] = f2bfu(eluf(v + bfu2f(p.aux[(size_t)r * p.auxld + col])));
                } else if constexpr (EPI == 6) {
                    float t = v + p.bias[col];
                    p.Cf[(size_t)r * p.ldc + col] = t;
                    p.Cb[(size_t)r * p.ldc + col] = f2bfu(t);
                } else if constexpr (EPI == 7) {
                    p.Cb[(size_t)r * p.ldc + col] = f2bfu(v + p.bias[col]);
                }
            }
        }
    }
}

template <int WM, int WN, int MF, int NF, int EPIa, int EPIb>
__global__ __launch_bounds__(WM * WN * 64) void gemmS(GP pa, GP pb, int nA) {
    constexpr int NT = WM * WN * 64;
    constexpr int BM = WM * MF * 16, BN = WN * NF * 16;
    constexpr int ABY = BM * 128, BBY = BN * 128;

    const int tid = threadIdx.x, w = tid >> 6, lane = tid & 63;
    const bool isA = (int)blockIdx.x < nA;
    GP p = isA ? pa : pb;
    const int bid = isA ? blockIdx.x : blockIdx.x - nA;
    const int bn = bid % p.gridN, bm = bid / p.gridN;
    const int r0 = bm * BM, c0 = bn * BN;
    const int wm = w / WN, wn = w % WN;

    __shared__ __attribute__((aligned(16))) char sm[2 * (ABY + BBY)];

    auto stage = [&](int kt, int buf) {
        char* s = sm + buf * (ABY + BBY);
#pragma unroll
        for (int it = 0; it < ABY / (NT * 16); ++it) {
            int bo = it * (NT * 16) + tid * 16;
            int row = bo >> 7, kb = bo & 127;
            int kbs = kb ^ ((row & 7) << 4);                       // pre-swizzled source
            GLOAD16(p.A + (size_t)(r0 + row) * p.lda + kt * 64 + (kbs >> 1), s + bo);
        }
        char* sb = s + ABY;
#pragma unroll
        for (int it = 0; it < BBY / (NT * 16); ++it) {
            int bo = it * (NT * 16) + tid * 16;
            int row = bo >> 7, kb = bo & 127;
            int kbs = kb ^ ((row & 7) << 4);
            GLOAD16(p.Bt + (size_t)(c0 + row) * p.K + kt * 64 + (kbs >> 1), sb + bo);
        }
    };

    f32x4 acc[MF][NF];
#pragma unroll
    for (int mf = 0; mf < MF; ++mf)
#pragma unroll
        for (int nf = 0; nf < NF; ++nf) acc[mf][nf] = (f32x4){0.f, 0.f, 0.f, 0.f};

    const int nk = p.K >> 6;
    stage(0, 0);
    asm volatile("s_waitcnt vmcnt(0)" ::: "memory");
    __syncthreads();
    int cur = 0;
    for (int kt = 0; kt < nk; ++kt) {
        if (kt + 1 < nk) stage(kt + 1, cur ^ 1);
        const char* s = sm + cur * (ABY + BBY);
#pragma unroll
        for (int ks = 0; ks < 2; ++ks) {
            const int kb = ks * 64 + ((lane >> 4) << 4);
            s16x8 aF[MF], bF[NF];
#pragma unroll
            for (int mf = 0; mf < MF; ++mf) {
                int rt = (wm * MF + mf) * 16 + (lane & 15);
                aF[mf] = *(const s16x8*)(s + rt * 128 + (kb ^ ((rt & 7) << 4)));
            }
#pragma unroll
            for (int nf = 0; nf < NF; ++nf) {
                int rt = (wn * NF + nf) * 16 + (lane & 15);
                bF[nf] = *(const s16x8*)(s + ABY + rt * 128 + (kb ^ ((rt & 7) << 4)));
            }
#pragma unroll
            for (int mf = 0; mf < MF; ++mf)
#pragma unroll
                for (int nf = 0; nf < NF; ++nf)
                    acc[mf][nf] = __builtin_amdgcn_mfma_f32_16x16x32_bf16(aF[mf], bF[nf], acc[mf][nf], 0, 0, 0);
        }
        asm volatile("s_waitcnt vmcnt(0)" ::: "memory");
        __syncthreads();
        cur ^= 1;
    }

    const int lrow4 = (lane >> 4) << 2, lcol = lane & 15;
    if (isA) epiS<EPIa, MF, NF>(p, acc, r0, c0, wm, wn, lrow4, lcol);
    else     epiS<EPIb, MF, NF>(p, acc, r0, c0, wm, wn, lrow4, lcol);
}

// ---------------------------------------------------------------------------
// k_gates: gx (K=1024) + full GRU epilogue (reads precomputed bf16 GHb)
// ---------------------------------------------------------------------------
template <bool FIRST>
__global__ __launch_bounds__(256) void k_gates(const u16* __restrict__ X, const u16* __restrict__ WihB,
                                               const float* __restrict__ bih, const float* __restrict__ bhh,
                                               const u16* __restrict__ GHb, float* __restrict__ hf32,
                                               u16* __restrict__ hallT) {
    constexpr int ABY = 64 * 128;       // 8 KB
    constexpr int BTB = 32 * 128;       // 4 KB per gate tile
    constexpr int TSZ = ABY + 3 * BTB;  // 20 KB
    const int tid = threadIdx.x, w = tid >> 6, lane = tid & 63;
    const int bm = blockIdx.x >> 6, bn = blockIdx.x & 63;
    const int r0 = bm * 64, c0 = bn * 32;
    const int wm = w >> 1, wn = w & 1;

    __shared__ __attribute__((aligned(16))) char sm[2 * TSZ];

    auto stage = [&](int kt, int buf) {
        char* s = sm + buf * TSZ;
#pragma unroll
        for (int it = 0; it < 2; ++it) {
            int bo = it * 4096 + tid * 16;
            int row = bo >> 7, kb = bo & 127;
            int kbs = kb ^ ((row & 7) << 4);
            GLOAD16(X + (size_t)(r0 + row) * 1024 + kt * 64 + (kbs >> 1), s + bo);
        }
        char* sb = s + ABY;
#pragma unroll
        for (int g = 0; g < 3; ++g) {
            int bo = tid * 16;
            int row = bo >> 7, kb = bo & 127;
            int kbs = kb ^ ((row & 7) << 4);
            GLOAD16(WihB + (size_t)(g * 2048 + c0 + row) * 1024 + kt * 64 + (kbs >> 1), sb + g * BTB + bo);
        }
    };

    f32x4 acc[3][2];
#pragma unroll
    for (int g = 0; g < 3; ++g)
#pragma unroll
        for (int mf = 0; mf < 2; ++mf) acc[g][mf] = (f32x4){0.f, 0.f, 0.f, 0.f};

    stage(0, 0);
    asm volatile("s_waitcnt vmcnt(0)" ::: "memory");
    __syncthreads();
    int cur = 0;
    for (int kt = 0; kt < 16; ++kt) {
        if (kt + 1 < 16) stage(kt + 1, cur ^ 1);
        const char* s = sm + cur * TSZ;
#pragma unroll
        for (int ks = 0; ks < 2; ++ks) {
            const int kb = ks * 64 + ((lane >> 4) << 4);
            s16x8 aF[2], bF[3];
#pragma unroll
            for (int mf = 0; mf < 2; ++mf) {
                int rt = (wm * 2 + mf) * 16 + (lane & 15);
                aF[mf] = *(const s16x8*)(s + rt * 128 + (kb ^ ((rt & 7) << 4)));
            }
#pragma unroll
            for (int g = 0; g < 3; ++g) {
                int rt = wn * 16 + (lane & 15);
                bF[g] = *(const s16x8*)(s + ABY + g * BTB + rt * 128 + (kb ^ ((rt & 7) << 4)));
            }
#pragma unroll
            for (int g = 0; g < 3; ++g)
#pragma unroll
                for (int mf = 0; mf < 2; ++mf)
                    acc[g][mf] = __builtin_amdgcn_mfma_f32_16x16x32_bf16(aF[mf], bF[g], acc[g][mf], 0, 0, 0);
        }
        asm volatile("s_waitcnt vmcnt(0)" ::: "memory");
        __syncthreads();
        cur ^= 1;
    }

    const int lrow4 = (lane >> 4) << 2, lcol = lane & 15;
    const int cc = c0 + wn * 16 + lcol;
#pragma unroll
    for (int mf = 0; mf < 2; ++mf) {
        int rr0 = r0 + (wm * 2 + mf) * 16 + lrow4;
#pragma unroll
        for (int j = 0; j < 4; ++j) {
            int rr = rr0 + j;
            float xr = acc[0][mf][j] + bih[cc];
            float xz = acc[1][mf][j] + bih[2048 + cc];
            float xn = acc[2][mf][j] + bih[4096 + cc];
            float hr_, hz_, hn_;
            if (FIRST) { hr_ = bhh[cc]; hz_ = bhh[2048 + cc]; hn_ = bhh[4096 + cc]; }
            else {
                const u16* g = GHb + (size_t)rr * 6144;
                hr_ = bfu2f(g[cc]); hz_ = bfu2f(g[2048 + cc]); hn_ = bfu2f(g[4096 + cc]);
            }
            float r = sigm(xr + hr_);
            float u = sigm(xz + hz_);
            float n = tanhf(xn + r * hn_);
            float hold = FIRST ? 0.f : hf32[(size_t)rr * 2048 + cc];
            float h = (1.f - u) * n + u * hold;
            hf32[(size_t)rr * 2048 + cc] = h;
            hallT[(size_t)rr * 2048 + cc] = f2bfu(h);
        }
    }
}

// ---------------------------------------------------------------------------
// small kernels
// ---------------------------------------------------------------------------
__global__ void k_init(double* acc) { acc[0] = 0.0; acc[1] = 0.0; }

__global__ void k_cast(const float* __restrict__ src, u16* __restrict__ dst, int n4) {
    int i = blockIdx.x * 256 + threadIdx.x;
    if (i >= n4) return;
    f32x4 v = *(const f32x4*)(src + (size_t)i * 4);
    s16x4 o;
    o[0] = (short)f2bfu(v[0]); o[1] = (short)f2bfu(v[1]);
    o[2] = (short)f2bfu(v[2]); o[3] = (short)f2bfu(v[3]);
    *(s16x4*)(dst + (size_t)i * 4) = o;
}

__global__ void k_transpose(const float* __restrict__ src, int sld, u16* __restrict__ dst, int K) {
    __shared__ float tile[32][33];
    int k0 = blockIdx.x * 32, n0 = blockIdx.y * 32;
    for (int r = threadIdx.y; r < 32; r += 8)
        tile[r][threadIdx.x] = src[(size_t)(k0 + r) * sld + n0 + threadIdx.x];
    __syncthreads();
    for (int r = threadIdx.y; r < 32; r += 8)
        dst[(size_t)(n0 + r) * K + k0 + threadIdx.x] = f2bfu(tile[threadIdx.x][r]);
}

__global__ void k_prep(const float* __restrict__ zsp, const float* __restrict__ zm,
                       const float* __restrict__ zsd, u16* __restrict__ flat) {
    size_t i = ((size_t)blockIdx.x * 256 + threadIdx.x) * 4;
    f32x4 v = *(const f32x4*)(zsp + i);
    int ch = ((int)(i >> 9)) & 3;
    float m = zm[ch], s = zsd[ch];
    s16x4 o;
    o[0] = (short)f2bfu((v[0] - m) / s); o[1] = (short)f2bfu((v[1] - m) / s);
    o[2] = (short)f2bfu((v[2] - m) / s); o[3] = (short)f2bfu((v[3] - m) / s);
    *(s16x4*)(flat + i) = o;
}

__global__ __launch_bounds__(256) void k_xpre0(const float* __restrict__ preW, const float* __restrict__ preb,
                                               const float* __restrict__ actions, u16* __restrict__ xout) {
    int b = blockIdx.x, tid = threadIdx.x;
    __shared__ float as[3];
    if (tid < 3) as[tid] = actions[(size_t)b * 64 * 3 + tid];
    __syncthreads();
    for (int j = tid; j < 1024; j += 256) {
        float s = preb[j] + as[0] * preW[1024 * 1024 + j] + as[1] * preW[1025 * 1024 + j] + as[2] * preW[1026 * 1024 + j];
        xout[(b << 10) + j] = f2bfu(eluf(s));
    }
}

// argmax per (b,l) + fused pre-MLP x for next step (KL deferred to k_kl)
__global__ __launch_bounds__(256) void k_smx(const float* __restrict__ Po, int* __restrict__ latidx_t,
                                             const u16* __restrict__ PreLatB, const float* __restrict__ preW,
                                             const float* __restrict__ preb,
                                             const float* __restrict__ actions, u16* __restrict__ xout,
                                             int tnext, int do_x) {
    int b = blockIdx.x, tid = threadIdx.x;
    const float* P = Po + (size_t)b * 1024;
    __shared__ int idxs[32];
    __shared__ float as[3];
    int grp = tid >> 5, c = tid & 31;
#pragma unroll
    for (int it = 0; it < 4; ++it) {
        int l = it * 8 + grp;
        float mv = P[l * 32 + c]; int mi = c;
#pragma unroll
        for (int o = 16; o > 0; o >>= 1) {
            float ov = __shfl_xor(mv, o, 32);
            int oi = __shfl_xor(mi, o, 32);
            if (ov > mv || (ov == mv && oi < mi)) { mv = ov; mi = oi; }
        }
        if (c == 0) idxs[l] = mi;
    }
    __syncthreads();
    if (tid < 32) latidx_t[(b << 5) + tid] = idxs[tid];
    if (do_x) {
        if (tid < 3) as[tid] = actions[((size_t)b * 64 + tnext) * 3 + tid];
        __syncthreads();
        const int j4 = tid * 4;
        f32x4 s = *(const f32x4*)(preb + j4);
#pragma unroll
        for (int cc = 0; cc < 3; ++cc) {
            f32x4 wv = *(const f32x4*)(preW + (size_t)(1024 + cc) * 1024 + j4);
            s[0] += as[cc] * wv[0]; s[1] += as[cc] * wv[1];
            s[2] += as[cc] * wv[2]; s[3] += as[cc] * wv[3];
        }
#pragma unroll
        for (int l = 0; l < 32; ++l) {
            s16x4 v = *(const s16x4*)(PreLatB + (size_t)((l << 5) + idxs[l]) * 1024 + j4);
            s[0] += bfu2f((u16)v[0]); s[1] += bfu2f((u16)v[1]);
            s[2] += bfu2f((u16)v[2]); s[3] += bfu2f((u16)v[3]);
        }
        s16x4 o;
        o[0] = (short)f2bfu(eluf(s[0])); o[1] = (short)f2bfu(eluf(s[1]));
        o[2] = (short)f2bfu(eluf(s[2])); o[3] = (short)f2bfu(eluf(s[3]));
        *(s16x4*)(xout + (b << 10) + j4) = o;
    }
}

// batched KL: one block per (t,b) row; reads bf16 post/prior logits
__global__ __launch_bounds__(256) void k_kl(const u16* __restrict__ PoAll, const u16* __restrict__ PrAll,
                                            float* __restrict__ klrow) {
    int m = blockIdx.x, tid = threadIdx.x;
    const u16* Po = PoAll + (size_t)m * 1024;
    const u16* Pr = PrAll + (size_t)m * 1024;
    __shared__ float klpart[32];
    int grp = tid >> 5, c = tid & 31;
#pragma unroll
    for (int it = 0; it < 4; ++it) {
        int l = it * 8 + grp;
        float po = bfu2f(Po[l * 32 + c]);
        float pr = bfu2f(Pr[l * 32 + c]);
        float mv = po, mq = pr;
#pragma unroll
        for (int o = 16; o > 0; o >>= 1) {
            mv = fmaxf(mv, __shfl_xor(mv, o, 32));
            mq = fmaxf(mq, __shfl_xor(mq, o, 32));
        }
        float ep = expf(po - mv), eq = expf(pr - mq);
        float sp = ep, sq = eq;
#pragma unroll
        for (int o = 16; o > 0; o >>= 1) { sp += __shfl_xor(sp, o, 32); sq += __shfl_xor(sq, o, 32); }
        float logp = po - mv - logf(sp);
        float logq = pr - mq - logf(sq);
        float klc = (ep / sp) * (logp - logq);
#pragma unroll
        for (int o = 16; o > 0; o >>= 1) klc += __shfl_xor(klc, o, 32);
        if (c == 0) klpart[l] = klc;
    }
    __syncthreads();
    if (tid == 0) {
        float kl = 0.f;
        for (int l = 0; l < 32; ++l) kl += klpart[l];
        klrow[m] = fmaxf(kl, 1.0f);
    }
}

__global__ __launch_bounds__(256) void k_latsum(const u16* __restrict__ LatB, const float* __restrict__ db1,
                                                const int* __restrict__ latidx_all, u16* __restrict__ latsum) {
    int m = blockIdx.x, tid = threadIdx.x;
    __shared__ int idxs[32];
    if (tid < 32) idxs[tid] = latidx_all[(size_t)m * 32 + tid];
    __syncthreads();
    const int j4 = tid * 4;
    f32x4 s = *(const f32x4*)(db1 + j4);
#pragma unroll
    for (int l = 0; l < 32; ++l) {
        s16x4 v = *(const s16x4*)(LatB + (size_t)((l << 5) + idxs[l]) * 1024 + j4);
        s[0] += bfu2f((u16)v[0]); s[1] += bfu2f((u16)v[1]);
        s[2] += bfu2f((u16)v[2]); s[3] += bfu2f((u16)v[3]);
    }
    s16x4 o;
    o[0] = (short)f2bfu(s[0]); o[1] = (short)f2bfu(s[1]);
    o[2] = (short)f2bfu(s[2]); o[3] = (short)f2bfu(s[3]);
    *(s16x4*)(latsum + (size_t)m * 1024 + j4) = o;
}

// NOTE: MUST be launched with 256 threads (was the r3-r5 bug: launched <<<1,1>>>,
// which dropped 16065/16128 KL rows -> exactly the observed 1.0859 error)
__global__ __launch_bounds__(256) void k_finalize(const double* __restrict__ acc,
                                                  const float* __restrict__ klrow, float* __restrict__ out) {
    __shared__ double ps[256];
    int tid = threadIdx.x;
    double s = 0.0;
    for (int i = tid; i < 16128; i += 256) s += (double)klrow[i];
    ps[tid] = s;
    __syncthreads();
    for (int o = 128; o > 0; o >>= 1) {
        if (tid < o) ps[tid] += ps[tid + o];
        __syncthreads();
    }
    if (tid == 0) out[0] = (float)(acc[0] / 33030144.0 + ps[0] / 16128.0);
}

// ---------------------------------------------------------------------------
extern "C" void kernel_launch(void* const* d_in, const int* in_sizes, int n_in,
                              void* d_out, int out_size, void* d_ws, size_t ws_size,
                              hipStream_t stream) {
    const float* zs      = (const float*)d_in[0];
    const float* actions = (const float*)d_in[1];
    const float* zmean   = (const float*)d_in[2];
    const float* zstd    = (const float*)d_in[3];
    const float* encW    = (const float*)d_in[4];
    const float* encb    = (const float*)d_in[5];
    const float* preW    = (const float*)d_in[6];
    const float* preb    = (const float*)d_in[7];
    const float* Wih     = (const float*)d_in[8];
    const float* Whh     = (const float*)d_in[9];
    const float* bih     = (const float*)d_in[10];
    const float* bhh     = (const float*)d_in[11];
    const float* tW1     = (const float*)d_in[12];
    const float* tb1     = (const float*)d_in[13];
    const float* tW2     = (const float*)d_in[14];
    const float* tb2     = (const float*)d_in[15];
    const float* rW1     = (const float*)d_in[16];
    const float* rb1     = (const float*)d_in[17];
    const float* rW2     = (const float*)d_in[18];
    const float* rb2     = (const float*)d_in[19];
    const float* dW1     = (const float*)d_in[20];
    const float* db1     = (const float*)d_in[21];
    const float* dW2     = (const float*)d_in[22];
    const float* db2     = (const float*)d_in[23];

    char* W = (char*)d_ws;
    size_t off = 0;
    auto take = [&](size_t b) { char* p = W + off; off += (b + 255) & ~(size_t)255; return p; };

    double* accum  = (double*)take(16);
    u16* encWbt = (u16*)take((size_t)1024 * 2048 * 2);
    u16* WihB   = (u16*)take((size_t)6144 * 1024 * 2);
    u16* WhhB   = (u16*)take((size_t)6144 * 2048 * 2);
    u16* l1B    = (u16*)take((size_t)2048 * 2048 * 2);   // [tW1t | rW1at]
    u16* tW2bt  = (u16*)take((size_t)1024 * 1024 * 2);
    u16* rW2bt  = (u16*)take((size_t)1024 * 1024 * 2);
    u16* rW1bbt = (u16*)take((size_t)1024 * 1024 * 2);
    u16* dW1abt = (u16*)take((size_t)1024 * 2048 * 2);
    u16* dW2bt  = (u16*)take((size_t)2048 * 1024 * 2);
    u16* PreLatB = (u16*)take((size_t)1024 * 1024 * 2);
    u16* LatB    = (u16*)take((size_t)1024 * 1024 * 2);
    u16* Hall   = (u16*)take((size_t)63 * 256 * 2048 * 2);
    int* latidx = (int*)take((size_t)63 * 256 * 32 * 4);
    u16* embR   = (u16*)take((size_t)16384 * 1024 * 2);   // scan emb; then PrAll; then latsum
    u16* enc    = (u16*)take((size_t)16384 * 1024 * 2);   // encoder out; then PoAll
    float* klrow = (float*)take((size_t)16128 * 4);
    u16* GHb    = (u16*)take((size_t)2 * 256 * 6144 * 2);
    float* hf32 = (float*)take((size_t)256 * 2048 * 4);
    u16* x_bf   = (u16*)take((size_t)256 * 1024 * 2);
    float* Po   = (float*)take((size_t)256 * 1024 * 4);
    u16* p1q1   = (u16*)take((size_t)256 * 1024 * 2);
    char* X     = take((size_t)17825792);                  // 17 MB: flatc/Xp/d1 (halved passes)

    u16* flatc = (u16*)X;                                  // 4096 x 2048 per pass
    u16* Xp    = (u16*)X;                                  // 8064 x 1024 per half
    u16* d1    = (u16*)X;                                  // 8064 x 1024 per half
    u16* PoAll = enc;                                      // enc dead after embR GEMM
    u16* PrAll = embR;                                     // embR dead after scan; consumed by k_kl before latsum

    k_init<<<1, 1, 0, stream>>>(accum);

    // weight conversion
    k_cast<<<6144, 256, 0, stream>>>(Wih, WihB, 6291456 / 4);
    k_cast<<<12288, 256, 0, stream>>>(Whh, WhhB, 12582912 / 4);
    k_cast<<<1024, 256, 0, stream>>>(preW, PreLatB, 262144);
    k_cast<<<1024, 256, 0, stream>>>(dW1 + (size_t)2048 * 1024, LatB, 262144);
    k_transpose<<<dim3(64, 32), dim3(32, 8), 0, stream>>>(encW, 1024, encWbt, 2048);
    k_transpose<<<dim3(64, 32), dim3(32, 8), 0, stream>>>(tW1, 1024, l1B, 2048);
    k_transpose<<<dim3(64, 32), dim3(32, 8), 0, stream>>>(rW1, 1024, l1B + (size_t)1024 * 2048, 2048);
    k_transpose<<<dim3(32, 32), dim3(32, 8), 0, stream>>>(tW2, 1024, tW2bt, 1024);
    k_transpose<<<dim3(32, 32), dim3(32, 8), 0, stream>>>(rW2, 1024, rW2bt, 1024);
    k_transpose<<<dim3(32, 32), dim3(32, 8), 0, stream>>>(rW1 + (size_t)2048 * 1024, 1024, rW1bbt, 1024);
    k_transpose<<<dim3(64, 32), dim3(32, 8), 0, stream>>>(dW1, 1024, dW1abt, 2048);
    k_transpose<<<dim3(32, 64), dim3(32, 8), 0, stream>>>(dW2, 2048, dW2bt, 1024);

    // phase 1: encoder (4 passes of 4096 rows) + embR precompute
    for (int pass = 0; pass < 4; ++pass) {
        k_prep<<<8192, 256, 0, stream>>>(zs + (size_t)pass * 4096 * 2048, zmean, zstd, flatc);
        GP e{}; e.A = flatc; e.lda = 2048; e.Bt = encWbt; e.Cb = enc + (size_t)pass * 4096 * 1024;
        e.ldc = 1024; e.bias = encb; e.K = 2048; e.gridN = 8;
        gemm_k<4, 4, 1, false><<<dim3(256), 256, 0, stream>>>(e, e);
    }
    {
        GP e{}; e.A = enc; e.lda = 1024; e.Bt = rW1bbt; e.Cb = embR; e.ldc = 1024;
        e.bias = rb1; e.K = 1024; e.gridN = 8;
        gemm_k<4, 4, 2, false><<<dim3(1024), 256, 0, stream>>>(e, e);
    }

    // phase 2: sequential scan (post-only path; prior deferred)
    k_xpre0<<<256, 256, 0, stream>>>(preW, preb, actions, x_bf);
    for (int t = 0; t < 63; ++t) {
        // k1: gx + GRU -> h_t
        if (t == 0)
            k_gates<true><<<256, 256, 0, stream>>>(x_bf, WihB, bih, bhh, GHb, hf32, Hall);
        else
            k_gates<false><<<256, 256, 0, stream>>>(x_bf, WihB, bih, bhh, GHb + (size_t)(t & 1) * 256 * 6144,
                                                    hf32, Hall + (size_t)t * 256 * 2048);
        // k2: gh(t+1) (bf16) || l1-post(t)
        {
            GP pa{}; pa.A = Hall + (size_t)t * 256 * 2048; pa.lda = 2048; pa.Bt = WhhB;
            pa.Cb = GHb + (size_t)((t + 1) & 1) * 256 * 6144; pa.ldc = 6144; pa.bias = bhh;
            pa.K = 2048; pa.gridN = 96;
            GP pb{}; pb.A = Hall + (size_t)t * 256 * 2048; pb.lda = 2048;
            pb.Bt = l1B + (size_t)1024 * 2048; pb.Cb = p1q1; pb.ldc = 1024;
            pb.aux = embR + (size_t)(t + 1) * 1024; pb.auxld = 65536;
            pb.K = 2048; pb.gridN = 16;
            int nA = (t < 62) ? 384 : 0;
            gemmS<2, 2, 2, 2, 7, 4><<<dim3(nA + 64), 256, 0, stream>>>(pa, pb, nA);
        }
        // k3: q-post -> Po (f32) + PoAll[t] (bf16)
        {
            GP q{}; q.A = p1q1; q.lda = 1024; q.Bt = rW2bt; q.Cf = Po; q.ldc = 1024;
            q.Cb = PoAll + (size_t)t * 256 * 1024; q.bias = rb2; q.K = 1024; q.gridN = 16;
            gemmS<2, 2, 2, 2, 6, 6><<<dim3(64), 256, 0, stream>>>(q, q, 64);
        }
        // k4: argmax + next x
        k_smx<<<256, 256, 0, stream>>>(Po, latidx + (size_t)t * 256 * 32,
                                       PreLatB, preW, preb, actions, x_bf, t + 1, (t < 62) ? 1 : 0);
    }

    // phase 3a: batched prior (2 halves of 8064 rows) + KL
    for (int half = 0; half < 2; ++half) {
        int m0 = half * 8064;
        GP e{}; e.A = Hall + (size_t)m0 * 2048; e.lda = 2048; e.Bt = l1B; e.Cb = Xp; e.ldc = 1024;
        e.bias = tb1; e.K = 2048; e.gridN = 8;
        gemm_k<4, 4, 1, false><<<dim3(504), 256, 0, stream>>>(e, e);
        GP q{}; q.A = Xp; q.lda = 1024; q.Bt = tW2bt; q.Cb = PrAll + (size_t)m0 * 1024; q.ldc = 1024;
        q.bias = tb2; q.K = 1024; q.gridN = 8;
        gemm_k<4, 4, 2, false><<<dim3(504), 256, 0, stream>>>(q, q);
    }
    k_kl<<<16128, 256, 0, stream>>>(PoAll, PrAll, klrow);

    // phase 3b: decoder + fused recon (2 halves; latsum overwrites embR/PrAll after k_kl)
    k_latsum<<<16128, 256, 0, stream>>>(LatB, db1, latidx, embR);
    for (int half = 0; half < 2; ++half) {
        int m0 = half * 8064;
        GP d{}; d.A = Hall + (size_t)m0 * 2048; d.lda = 2048; d.Bt = dW1abt; d.Cb = d1; d.ldc = 1024;
        d.aux = embR + (size_t)m0 * 1024; d.auxld = 1024; d.K = 2048; d.gridN = 8;
        gemm_k<4, 4, 4, false><<<dim3(504), 256, 0, stream>>>(d, d);
        GP d2{}; d2.A = d1; d2.lda = 1024; d2.Bt = dW2bt; d2.ldc = 2048; d2.bias = db2;
        d2.zs = zs; d2.zmean = zmean; d2.zstd = zstd; d2.accum = accum; d2.K = 1024; d2.gridN = 16;
        d2.rbase = m0;
        gemm_k<4, 4, 5, false><<<dim3(1008), 256, 0, stream>>>(d2, d2);
    }
    k_finalize<<<1, 256, 0, stream>>>(accum, klrow, (float*)d_out);
}

// Round 7
// 3622.894 us; speedup vs baseline: 1.7074x; 1.2109x over previous
//
#include <hip/hip_runtime.h>
#include <hip/hip_bf16.h>
#include <math.h>

typedef unsigned short u16;
typedef __attribute__((ext_vector_type(8))) short s16x8;
typedef __attribute__((ext_vector_type(4))) short s16x4;
typedef __attribute__((ext_vector_type(4))) float f32x4;

#define DEVI static __device__ __forceinline__

DEVI u16 f2bfu(float f) {
    unsigned u = __float_as_uint(f);
    unsigned r = (u + 0x7fffu + ((u >> 16) & 1u)) >> 16;
    return (u16)r;
}
DEVI float bfu2f(u16 u) { return __uint_as_float(((unsigned)u) << 16); }
DEVI float eluf(float x) { return x > 0.f ? x : (expf(x) - 1.f); }
DEVI float sigm(float x) { return 1.f / (1.f + expf(-x)); }

#define GLOAD16(gsrc, ldst)                                                            \
    __builtin_amdgcn_global_load_lds(                                                  \
        (__attribute__((address_space(1))) void*)(void*)(gsrc),                        \
        (__attribute__((address_space(3))) void*)(ldst), 16, 0, 0)

template <int N> DEVI void vmwait();
template <> DEVI void vmwait<0>() { asm volatile("s_waitcnt vmcnt(0)" ::: "memory"); }
template <> DEVI void vmwait<4>() { asm volatile("s_waitcnt vmcnt(4)" ::: "memory"); }
template <> DEVI void vmwait<5>() { asm volatile("s_waitcnt vmcnt(5)" ::: "memory"); }

struct GP {
    const u16* A; int lda;
    const u16* Bt;
    float* Cf; u16* Cb; int ldc;
    const float* bias;
    const u16* aux; int auxld;
    const float* zs;               // EPI5
    const float* zmean; const float* zstd;
    double* accum;
    int* idx;                      // EPI8: argmax out
    int K; int gridN; int rbase;
};

// ---------------------------------------------------------------------------
// Legacy GEMM (BK=32, 4 waves, 2-phase) — encoder / priors / decoder
// ---------------------------------------------------------------------------
template <int MF, int NF, int EPI, bool DUAL>
__global__ __launch_bounds__(256) void gemm_k(GP p0, GP p1) {
    GP p = (DUAL && blockIdx.y) ? p1 : p0;
    constexpr int BM = 32 * MF, BN = 32 * NF;
    constexpr int ABYTES = BM * 64, BBYTES = BN * 64;

    const int tid = threadIdx.x;
    const int w = tid >> 6, lane = tid & 63;
    const int bid = blockIdx.x;
    const int bn = bid % p.gridN, bm = bid / p.gridN;
    const int r0 = bm * BM, c0 = bn * BN;
    const int wm = w >> 1, wn = w & 1;

    __shared__ __attribute__((aligned(16))) char sm[2 * (ABYTES + BBYTES)];
    __shared__ float ps[4];

    auto stage = [&](int kt, int buf) {
        char* s = sm + buf * (ABYTES + BBYTES);
        const u16* Ag = p.A + (size_t)r0 * p.lda + kt * 32;
#pragma unroll
        for (int it = 0; it < BM / 64; ++it) {
            int bo = it * 4096 + w * 1024 + lane * 16;
            int row = bo >> 6, kg = (bo & 63) >> 4;
            GLOAD16(Ag + (size_t)row * p.lda + kg * 8, s + bo);
        }
        const u16* Bg = p.Bt + (size_t)c0 * p.K + kt * 32;
        char* sb = s + ABYTES;
#pragma unroll
        for (int it = 0; it < BN / 64; ++it) {
            int bo = it * 4096 + w * 1024 + lane * 16;
            int row = bo >> 6, kg = (bo & 63) >> 4;
            GLOAD16(Bg + (size_t)row * p.K + kg * 8, sb + bo);
        }
    };

    f32x4 acc[MF][NF];
#pragma unroll
    for (int mf = 0; mf < MF; ++mf)
#pragma unroll
        for (int nf = 0; nf < NF; ++nf) acc[mf][nf] = (f32x4){0.f, 0.f, 0.f, 0.f};

    const int nk = p.K >> 5;
    stage(0, 0);
    asm volatile("s_waitcnt vmcnt(0)" ::: "memory");
    __syncthreads();
    int cur = 0;
    for (int kt = 0; kt < nk; ++kt) {
        if (kt + 1 < nk) stage(kt + 1, cur ^ 1);
        const char* s = sm + cur * (ABYTES + BBYTES);
        s16x8 aF[MF], bF[NF];
#pragma unroll
        for (int mf = 0; mf < MF; ++mf)
            aF[mf] = *(const s16x8*)(s + ((wm * MF + mf) * 16 + (lane & 15)) * 64 + (lane >> 4) * 16);
#pragma unroll
        for (int nf = 0; nf < NF; ++nf)
            bF[nf] = *(const s16x8*)(s + ABYTES + ((wn * NF + nf) * 16 + (lane & 15)) * 64 + (lane >> 4) * 16);
#pragma unroll
        for (int mf = 0; mf < MF; ++mf)
#pragma unroll
            for (int nf = 0; nf < NF; ++nf)
                acc[mf][nf] = __builtin_amdgcn_mfma_f32_16x16x32_bf16(aF[mf], bF[nf], acc[mf][nf], 0, 0, 0);
        asm volatile("s_waitcnt vmcnt(0)" ::: "memory");
        __syncthreads();
        cur ^= 1;
    }

    const int lrow4 = (lane >> 4) << 2, lcol = lane & 15;
    float lsum = 0.f;
#pragma unroll
    for (int mf = 0; mf < MF; ++mf) {
        int rowb = r0 + (wm * MF + mf) * 16 + lrow4;
#pragma unroll
        for (int nf = 0; nf < NF; ++nf) {
            int col = c0 + (wn * NF + nf) * 16 + lcol;
#pragma unroll
            for (int j = 0; j < 4; ++j) {
                float v = acc[mf][nf][j];
                int r = rowb + j;
                if constexpr (EPI == 1) {
                    p.Cb[(size_t)r * p.ldc + col] = f2bfu(eluf(v + p.bias[col]));
                } else if constexpr (EPI == 2) {
                    p.Cb[(size_t)r * p.ldc + col] = f2bfu(v + p.bias[col]);
                } else if constexpr (EPI == 4) {
                    p.Cb[(size_t)r * p.ldc + col] = f2bfu(eluf(v + bfu2f(p.aux[(size_t)r * p.auxld + col])));
                } else if constexpr (EPI == 5) {
                    v += p.bias[col];
                    int R = r + p.rbase;
                    int tt = R >> 8, b = R & 255;
                    int ch = col >> 9;
                    float z = (p.zs[((size_t)b * 64 + tt + 1) * 2048 + col] - p.zmean[ch]) / p.zstd[ch];
                    float d = v - z;
                    lsum += d * d;
                }
            }
        }
    }
    if constexpr (EPI == 5) {
#pragma unroll
        for (int o = 32; o > 0; o >>= 1) lsum += __shfl_down(lsum, o, 64);
        if (lane == 0) ps[w] = lsum;
        __syncthreads();
        if (tid == 0) {
            double s = (double)ps[0] + (double)ps[1] + (double)ps[2] + (double)ps[3];
            atomicAdd(p.accum, s);
        }
    }
}

// ---------------------------------------------------------------------------
// Scan GEMM: BK=64, T2 XOR-swizzle, 3-deep counted-vmcnt pipeline (T3/T4).
// Validated: r3 binary with this exact loop produced bit-identical output.
// EPI4: elu(v + aux) -> bf16 ; EPI7: v+bias -> bf16 (gh)
// EPI8: v+bias -> bf16 post logits + fused per-(row,latent) argmax -> idx
// ---------------------------------------------------------------------------
template <int EPI, int MF, int NF>
DEVI void epiS(const GP& p, f32x4 (&acc)[MF][NF], int r0, int c0, int wm, int wn,
               int lrow4, int lcol) {
#pragma unroll
    for (int mf = 0; mf < MF; ++mf) {
        int rowb = r0 + (wm * MF + mf) * 16 + lrow4;
#pragma unroll
        for (int nf = 0; nf < NF; ++nf) {
            int col = c0 + (wn * NF + nf) * 16 + lcol;
#pragma unroll
            for (int j = 0; j < 4; ++j) {
                float v = acc[mf][nf][j];
                int r = rowb + j;
                if constexpr (EPI == 4) {
                    p.Cb[(size_t)r * p.ldc + col] = f2bfu(eluf(v + bfu2f(p.aux[(size_t)r * p.auxld + col])));
                } else if constexpr (EPI == 7) {
                    p.Cb[(size_t)r * p.ldc + col] = f2bfu(v + p.bias[col]);
                }
            }
        }
    }
}

template <int WM, int WN, int MF, int NF, int EPIa, int EPIb>
__global__ __launch_bounds__(WM * WN * 64) void gemmS(GP pa, GP pb, int nA) {
    constexpr int NT = WM * WN * 64;
    constexpr int BM = WM * MF * 16, BN = WN * NF * 16;
    constexpr int ABY = BM * 128, BBY = BN * 128;
    constexpr int LPT = (ABY + BBY) / (NT * 16);

    const int tid = threadIdx.x, w = tid >> 6, lane = tid & 63;
    const bool isA = (int)blockIdx.x < nA;
    GP p = isA ? pa : pb;
    const int bid = isA ? blockIdx.x : blockIdx.x - nA;
    const int bn = bid % p.gridN, bm = bid / p.gridN;
    const int r0 = bm * BM, c0 = bn * BN;
    const int wm = w / WN, wn = w % WN;

    __shared__ __attribute__((aligned(16))) char sm[3 * (ABY + BBY)];

    auto stage = [&](int kt, int buf) {
        char* s = sm + buf * (ABY + BBY);
#pragma unroll
        for (int it = 0; it < ABY / (NT * 16); ++it) {
            int bo = it * (NT * 16) + tid * 16;
            int row = bo >> 7, kb = bo & 127;
            int kbs = kb ^ ((row & 7) << 4);                       // pre-swizzled source
            GLOAD16(p.A + (size_t)(r0 + row) * p.lda + kt * 64 + (kbs >> 1), s + bo);
        }
        char* sb = s + ABY;
#pragma unroll
        for (int it = 0; it < BBY / (NT * 16); ++it) {
            int bo = it * (NT * 16) + tid * 16;
            int row = bo >> 7, kb = bo & 127;
            int kbs = kb ^ ((row & 7) << 4);
            GLOAD16(p.Bt + (size_t)(c0 + row) * p.K + kt * 64 + (kbs >> 1), sb + bo);
        }
    };

    f32x4 acc[MF][NF];
#pragma unroll
    for (int mf = 0; mf < MF; ++mf)
#pragma unroll
        for (int nf = 0; nf < NF; ++nf) acc[mf][nf] = (f32x4){0.f, 0.f, 0.f, 0.f};

    const int nk = p.K >> 6;
    stage(0, 0);
    stage(1, 1);
    int b0 = 0, b1 = 1, b2 = 2;
    for (int kt = 0; kt < nk; ++kt) {
        if (kt < nk - 1) vmwait<LPT>(); else vmwait<0>();
        __builtin_amdgcn_sched_barrier(0);
        __builtin_amdgcn_s_barrier();
        if (kt + 2 < nk) stage(kt + 2, b2);
        const char* s = sm + b0 * (ABY + BBY);
#pragma unroll
        for (int ks = 0; ks < 2; ++ks) {
            const int kb = ks * 64 + ((lane >> 4) << 4);
            s16x8 aF[MF], bF[NF];
#pragma unroll
            for (int mf = 0; mf < MF; ++mf) {
                int rt = (wm * MF + mf) * 16 + (lane & 15);
                aF[mf] = *(const s16x8*)(s + rt * 128 + (kb ^ ((rt & 7) << 4)));
            }
#pragma unroll
            for (int nf = 0; nf < NF; ++nf) {
                int rt = (wn * NF + nf) * 16 + (lane & 15);
                bF[nf] = *(const s16x8*)(s + ABY + rt * 128 + (kb ^ ((rt & 7) << 4)));
            }
#pragma unroll
            for (int mf = 0; mf < MF; ++mf)
#pragma unroll
                for (int nf = 0; nf < NF; ++nf)
                    acc[mf][nf] = __builtin_amdgcn_mfma_f32_16x16x32_bf16(aF[mf], bF[nf], acc[mf][nf], 0, 0, 0);
        }
        int t_ = b0; b0 = b1; b1 = b2; b2 = t_;
    }

    const int lrow4 = (lane >> 4) << 2, lcol = lane & 15;
    if constexpr (EPIa == 8) {
        // requires NF==2, BN=64: wave (wm,wn) holds one full 32-class latent
        // group (lat = c0/32 + wn) for 8 rows x 2 nf fragments.
        const int lat = (c0 >> 5) + wn;
#pragma unroll
        for (int mf = 0; mf < MF; ++mf) {
#pragma unroll
            for (int j = 0; j < 4; ++j) {
                int r = r0 + (wm * MF + mf) * 16 + lrow4 + j;
                int col0 = c0 + wn * 32 + lcol;
                float v0 = acc[mf][0][j] + p.bias[col0];
                float v1 = acc[mf][1][j] + p.bias[col0 + 16];
                p.Cb[(size_t)r * p.ldc + col0] = f2bfu(v0);
                p.Cb[(size_t)r * p.ldc + col0 + 16] = f2bfu(v1);
                float mv; int mi;
                if (v1 > v0) { mv = v1; mi = lcol + 16; } else { mv = v0; mi = lcol; }
#pragma unroll
                for (int o = 8; o >= 1; o >>= 1) {
                    float ov = __shfl_xor(mv, o, 64);
                    int oi = __shfl_xor(mi, o, 64);
                    if (ov > mv || (ov == mv && oi < mi)) { mv = ov; mi = oi; }
                }
                if (lcol == 0) p.idx[(size_t)r * 32 + lat] = mi;
            }
        }
    } else {
        if (isA) epiS<EPIa, MF, NF>(p, acc, r0, c0, wm, wn, lrow4, lcol);
        else     epiS<EPIb, MF, NF>(p, acc, r0, c0, wm, wn, lrow4, lcol);
    }
}

// ---------------------------------------------------------------------------
// k_gates: gx (K=1024) + full GRU epilogue; 3-deep pipeline (LPT=5, r3-proven)
// ---------------------------------------------------------------------------
template <bool FIRST>
__global__ __launch_bounds__(256) void k_gates(const u16* __restrict__ X, const u16* __restrict__ WihB,
                                               const float* __restrict__ bih, const float* __restrict__ bhh,
                                               const u16* __restrict__ GHb, float* __restrict__ hf32,
                                               u16* __restrict__ hallT) {
    constexpr int ABY = 64 * 128;       // 8 KB
    constexpr int BTB = 32 * 128;       // 4 KB per gate tile
    constexpr int TSZ = ABY + 3 * BTB;  // 20 KB
    const int tid = threadIdx.x, w = tid >> 6, lane = tid & 63;
    const int bm = blockIdx.x >> 6, bn = blockIdx.x & 63;
    const int r0 = bm * 64, c0 = bn * 32;
    const int wm = w >> 1, wn = w & 1;

    __shared__ __attribute__((aligned(16))) char sm[3 * TSZ];

    auto stage = [&](int kt, int buf) {
        char* s = sm + buf * TSZ;
#pragma unroll
        for (int it = 0; it < 2; ++it) {
            int bo = it * 4096 + tid * 16;
            int row = bo >> 7, kb = bo & 127;
            int kbs = kb ^ ((row & 7) << 4);
            GLOAD16(X + (size_t)(r0 + row) * 1024 + kt * 64 + (kbs >> 1), s + bo);
        }
        char* sb = s + ABY;
#pragma unroll
        for (int g = 0; g < 3; ++g) {
            int bo = tid * 16;
            int row = bo >> 7, kb = bo & 127;
            int kbs = kb ^ ((row & 7) << 4);
            GLOAD16(WihB + (size_t)(g * 2048 + c0 + row) * 1024 + kt * 64 + (kbs >> 1), sb + g * BTB + bo);
        }
    };

    f32x4 acc[3][2];
#pragma unroll
    for (int g = 0; g < 3; ++g)
#pragma unroll
        for (int mf = 0; mf < 2; ++mf) acc[g][mf] = (f32x4){0.f, 0.f, 0.f, 0.f};

    stage(0, 0);
    stage(1, 1);
    int b0 = 0, b1 = 1, b2 = 2;
    for (int kt = 0; kt < 16; ++kt) {
        if (kt < 15) vmwait<5>(); else vmwait<0>();
        __builtin_amdgcn_sched_barrier(0);
        __builtin_amdgcn_s_barrier();
        if (kt + 2 < 16) stage(kt + 2, b2);
        const char* s = sm + b0 * TSZ;
#pragma unroll
        for (int ks = 0; ks < 2; ++ks) {
            const int kb = ks * 64 + ((lane >> 4) << 4);
            s16x8 aF[2], bF[3];
#pragma unroll
            for (int mf = 0; mf < 2; ++mf) {
                int rt = (wm * 2 + mf) * 16 + (lane & 15);
                aF[mf] = *(const s16x8*)(s + rt * 128 + (kb ^ ((rt & 7) << 4)));
            }
#pragma unroll
            for (int g = 0; g < 3; ++g) {
                int rt = wn * 16 + (lane & 15);
                bF[g] = *(const s16x8*)(s + ABY + g * BTB + rt * 128 + (kb ^ ((rt & 7) << 4)));
            }
#pragma unroll
            for (int g = 0; g < 3; ++g)
#pragma unroll
                for (int mf = 0; mf < 2; ++mf)
                    acc[g][mf] = __builtin_amdgcn_mfma_f32_16x16x32_bf16(aF[mf], bF[g], acc[g][mf], 0, 0, 0);
        }
        int t_ = b0; b0 = b1; b1 = b2; b2 = t_;
    }

    const int lrow4 = (lane >> 4) << 2, lcol = lane & 15;
    const int cc = c0 + wn * 16 + lcol;
#pragma unroll
    for (int mf = 0; mf < 2; ++mf) {
        int rr0 = r0 + (wm * 2 + mf) * 16 + lrow4;
#pragma unroll
        for (int j = 0; j < 4; ++j) {
            int rr = rr0 + j;
            float xr = acc[0][mf][j] + bih[cc];
            float xz = acc[1][mf][j] + bih[2048 + cc];
            float xn = acc[2][mf][j] + bih[4096 + cc];
            float hr_, hz_, hn_;
            if (FIRST) { hr_ = bhh[cc]; hz_ = bhh[2048 + cc]; hn_ = bhh[4096 + cc]; }
            else {
                const u16* g = GHb + (size_t)rr * 6144;
                hr_ = bfu2f(g[cc]); hz_ = bfu2f(g[2048 + cc]); hn_ = bfu2f(g[4096 + cc]);
            }
            float r = sigm(xr + hr_);
            float u = sigm(xz + hz_);
            float n = tanhf(xn + r * hn_);
            float hold = FIRST ? 0.f : hf32[(size_t)rr * 2048 + cc];
            float h = (1.f - u) * n + u * hold;
            hf32[(size_t)rr * 2048 + cc] = h;
            hallT[(size_t)rr * 2048 + cc] = f2bfu(h);
        }
    }
}

// ---------------------------------------------------------------------------
// small kernels
// ---------------------------------------------------------------------------
__global__ void k_init(double* acc) { acc[0] = 0.0; acc[1] = 0.0; }

__global__ void k_cast(const float* __restrict__ src, u16* __restrict__ dst, int n4) {
    int i = blockIdx.x * 256 + threadIdx.x;
    if (i >= n4) return;
    f32x4 v = *(const f32x4*)(src + (size_t)i * 4);
    s16x4 o;
    o[0] = (short)f2bfu(v[0]); o[1] = (short)f2bfu(v[1]);
    o[2] = (short)f2bfu(v[2]); o[3] = (short)f2bfu(v[3]);
    *(s16x4*)(dst + (size_t)i * 4) = o;
}

__global__ void k_transpose(const float* __restrict__ src, int sld, u16* __restrict__ dst, int K) {
    __shared__ float tile[32][33];
    int k0 = blockIdx.x * 32, n0 = blockIdx.y * 32;
    for (int r = threadIdx.y; r < 32; r += 8)
        tile[r][threadIdx.x] = src[(size_t)(k0 + r) * sld + n0 + threadIdx.x];
    __syncthreads();
    for (int r = threadIdx.y; r < 32; r += 8)
        dst[(size_t)(n0 + r) * K + k0 + threadIdx.x] = f2bfu(tile[threadIdx.x][r]);
}

__global__ void k_prep(const float* __restrict__ zsp, const float* __restrict__ zm,
                       const float* __restrict__ zsd, u16* __restrict__ flat) {
    size_t i = ((size_t)blockIdx.x * 256 + threadIdx.x) * 4;
    f32x4 v = *(const f32x4*)(zsp + i);
    int ch = ((int)(i >> 9)) & 3;
    float m = zm[ch], s = zsd[ch];
    s16x4 o;
    o[0] = (short)f2bfu((v[0] - m) / s); o[1] = (short)f2bfu((v[1] - m) / s);
    o[2] = (short)f2bfu((v[2] - m) / s); o[3] = (short)f2bfu((v[3] - m) / s);
    *(s16x4*)(flat + i) = o;
}

__global__ __launch_bounds__(256) void k_xpre0(const float* __restrict__ preW, const float* __restrict__ preb,
                                               const float* __restrict__ actions, u16* __restrict__ xout) {
    int b = blockIdx.x, tid = threadIdx.x;
    __shared__ float as[3];
    if (tid < 3) as[tid] = actions[(size_t)b * 64 * 3 + tid];
    __syncthreads();
    for (int j = tid; j < 1024; j += 256) {
        float s = preb[j] + as[0] * preW[1024 * 1024 + j] + as[1] * preW[1025 * 1024 + j] + as[2] * preW[1026 * 1024 + j];
        xout[(b << 10) + j] = f2bfu(eluf(s));
    }
}

// x-gen only (argmax now fused into k3's EPI8 epilogue)
__global__ __launch_bounds__(256) void k_xgen(const int* __restrict__ latidx_t,
                                              const u16* __restrict__ PreLatB, const float* __restrict__ preW,
                                              const float* __restrict__ preb,
                                              const float* __restrict__ actions, u16* __restrict__ xout,
                                              int tnext) {
    int b = blockIdx.x, tid = threadIdx.x;
    __shared__ int idxs[32];
    __shared__ float as[3];
    if (tid < 32) idxs[tid] = latidx_t[(b << 5) + tid];
    if (tid >= 64 && tid < 67) as[tid - 64] = actions[((size_t)b * 64 + tnext) * 3 + (tid - 64)];
    __syncthreads();
    const int j4 = tid * 4;
    f32x4 s = *(const f32x4*)(preb + j4);
#pragma unroll
    for (int cc = 0; cc < 3; ++cc) {
        f32x4 wv = *(const f32x4*)(preW + (size_t)(1024 + cc) * 1024 + j4);
        s[0] += as[cc] * wv[0]; s[1] += as[cc] * wv[1];
        s[2] += as[cc] * wv[2]; s[3] += as[cc] * wv[3];
    }
#pragma unroll
    for (int l = 0; l < 32; ++l) {
        s16x4 v = *(const s16x4*)(PreLatB + (size_t)((l << 5) + idxs[l]) * 1024 + j4);
        s[0] += bfu2f((u16)v[0]); s[1] += bfu2f((u16)v[1]);
        s[2] += bfu2f((u16)v[2]); s[3] += bfu2f((u16)v[3]);
    }
    s16x4 o;
    o[0] = (short)f2bfu(eluf(s[0])); o[1] = (short)f2bfu(eluf(s[1]));
    o[2] = (short)f2bfu(eluf(s[2])); o[3] = (short)f2bfu(eluf(s[3]));
    *(s16x4*)(xout + (b << 10) + j4) = o;
}

// batched KL: one block per (t,b) row; reads bf16 post/prior logits
__global__ __launch_bounds__(256) void k_kl(const u16* __restrict__ PoAll, const u16* __restrict__ PrAll,
                                            float* __restrict__ klrow) {
    int m = blockIdx.x, tid = threadIdx.x;
    const u16* Po = PoAll + (size_t)m * 1024;
    const u16* Pr = PrAll + (size_t)m * 1024;
    __shared__ float klpart[32];
    int grp = tid >> 5, c = tid & 31;
#pragma unroll
    for (int it = 0; it < 4; ++it) {
        int l = it * 8 + grp;
        float po = bfu2f(Po[l * 32 + c]);
        float pr = bfu2f(Pr[l * 32 + c]);
        float mv = po, mq = pr;
#pragma unroll
        for (int o = 16; o > 0; o >>= 1) {
            mv = fmaxf(mv, __shfl_xor(mv, o, 32));
            mq = fmaxf(mq, __shfl_xor(mq, o, 32));
        }
        float ep = expf(po - mv), eq = expf(pr - mq);
        float sp = ep, sq = eq;
#pragma unroll
        for (int o = 16; o > 0; o >>= 1) { sp += __shfl_xor(sp, o, 32); sq += __shfl_xor(sq, o, 32); }
        float logp = po - mv - logf(sp);
        float logq = pr - mq - logf(sq);
        float klc = (ep / sp) * (logp - logq);
#pragma unroll
        for (int o = 16; o > 0; o >>= 1) klc += __shfl_xor(klc, o, 32);
        if (c == 0) klpart[l] = klc;
    }
    __syncthreads();
    if (tid == 0) {
        float kl = 0.f;
        for (int l = 0; l < 32; ++l) kl += klpart[l];
        klrow[m] = fmaxf(kl, 1.0f);
    }
}

__global__ __launch_bounds__(256) void k_latsum(const u16* __restrict__ LatB, const float* __restrict__ db1,
                                                const int* __restrict__ latidx_all, u16* __restrict__ latsum) {
    int m = blockIdx.x, tid = threadIdx.x;
    __shared__ int idxs[32];
    if (tid < 32) idxs[tid] = latidx_all[(size_t)m * 32 + tid];
    __syncthreads();
    const int j4 = tid * 4;
    f32x4 s = *(const f32x4*)(db1 + j4);
#pragma unroll
    for (int l = 0; l < 32; ++l) {
        s16x4 v = *(const s16x4*)(LatB + (size_t)((l << 5) + idxs[l]) * 1024 + j4);
        s[0] += bfu2f((u16)v[0]); s[1] += bfu2f((u16)v[1]);
        s[2] += bfu2f((u16)v[2]); s[3] += bfu2f((u16)v[3]);
    }
    s16x4 o;
    o[0] = (short)f2bfu(s[0]); o[1] = (short)f2bfu(s[1]);
    o[2] = (short)f2bfu(s[2]); o[3] = (short)f2bfu(s[3]);
    *(s16x4*)(latsum + (size_t)m * 1024 + j4) = o;
}

// NOTE: MUST be launched with 256 threads (r3-r5 bug: was <<<1,1>>>)
__global__ __launch_bounds__(256) void k_finalize(const double* __restrict__ acc,
                                                  const float* __restrict__ klrow, float* __restrict__ out) {
    __shared__ double ps[256];
    int tid = threadIdx.x;
    double s = 0.0;
    for (int i = tid; i < 16128; i += 256) s += (double)klrow[i];
    ps[tid] = s;
    __syncthreads();
    for (int o = 128; o > 0; o >>= 1) {
        if (tid < o) ps[tid] += ps[tid + o];
        __syncthreads();
    }
    if (tid == 0) out[0] = (float)(acc[0] / 33030144.0 + ps[0] / 16128.0);
}

// ---------------------------------------------------------------------------
extern "C" void kernel_launch(void* const* d_in, const int* in_sizes, int n_in,
                              void* d_out, int out_size, void* d_ws, size_t ws_size,
                              hipStream_t stream) {
    const float* zs      = (const float*)d_in[0];
    const float* actions = (const float*)d_in[1];
    const float* zmean   = (const float*)d_in[2];
    const float* zstd    = (const float*)d_in[3];
    const float* encW    = (const float*)d_in[4];
    const float* encb    = (const float*)d_in[5];
    const float* preW    = (const float*)d_in[6];
    const float* preb    = (const float*)d_in[7];
    const float* Wih     = (const float*)d_in[8];
    const float* Whh     = (const float*)d_in[9];
    const float* bih     = (const float*)d_in[10];
    const float* bhh     = (const float*)d_in[11];
    const float* tW1     = (const float*)d_in[12];
    const float* tb1     = (const float*)d_in[13];
    const float* tW2     = (const float*)d_in[14];
    const float* tb2     = (const float*)d_in[15];
    const float* rW1     = (const float*)d_in[16];
    const float* rb1     = (const float*)d_in[17];
    const float* rW2     = (const float*)d_in[18];
    const float* rb2     = (const float*)d_in[19];
    const float* dW1     = (const float*)d_in[20];
    const float* db1     = (const float*)d_in[21];
    const float* dW2     = (const float*)d_in[22];
    const float* db2     = (const float*)d_in[23];

    char* W = (char*)d_ws;
    size_t off = 0;
    auto take = [&](size_t b) { char* p = W + off; off += (b + 255) & ~(size_t)255; return p; };

    double* accum  = (double*)take(16);
    u16* encWbt = (u16*)take((size_t)1024 * 2048 * 2);
    u16* WihB   = (u16*)take((size_t)6144 * 1024 * 2);
    u16* WhhB   = (u16*)take((size_t)6144 * 2048 * 2);
    u16* l1B    = (u16*)take((size_t)2048 * 2048 * 2);   // [tW1t | rW1at]
    u16* tW2bt  = (u16*)take((size_t)1024 * 1024 * 2);
    u16* rW2bt  = (u16*)take((size_t)1024 * 1024 * 2);
    u16* rW1bbt = (u16*)take((size_t)1024 * 1024 * 2);
    u16* dW1abt = (u16*)take((size_t)1024 * 2048 * 2);
    u16* dW2bt  = (u16*)take((size_t)2048 * 1024 * 2);
    u16* PreLatB = (u16*)take((size_t)1024 * 1024 * 2);
    u16* LatB    = (u16*)take((size_t)1024 * 1024 * 2);
    u16* Hall   = (u16*)take((size_t)63 * 256 * 2048 * 2);
    int* latidx = (int*)take((size_t)63 * 256 * 32 * 4);
    u16* embR   = (u16*)take((size_t)16384 * 1024 * 2);   // scan emb; then PrAll; then latsum
    u16* enc    = (u16*)take((size_t)16384 * 1024 * 2);   // encoder out; then PoAll
    float* klrow = (float*)take((size_t)16128 * 4);
    u16* GHb    = (u16*)take((size_t)2 * 256 * 6144 * 2);
    float* hf32 = (float*)take((size_t)256 * 2048 * 4);
    u16* x_bf   = (u16*)take((size_t)256 * 1024 * 2);
    u16* p1q1   = (u16*)take((size_t)256 * 1024 * 2);
    char* X     = take((size_t)17825792);                  // 17 MB: flatc/Xp/d1

    u16* flatc = (u16*)X;                                  // 4096 x 2048 per pass
    u16* Xp    = (u16*)X;                                  // 8064 x 1024 per half
    u16* d1    = (u16*)X;                                  // 8064 x 1024 per half
    u16* PoAll = enc;                                      // enc dead after embR GEMM
    u16* PrAll = embR;                                     // embR dead after scan; consumed by k_kl before latsum

    k_init<<<1, 1, 0, stream>>>(accum);

    // weight conversion
    k_cast<<<6144, 256, 0, stream>>>(Wih, WihB, 6291456 / 4);
    k_cast<<<12288, 256, 0, stream>>>(Whh, WhhB, 12582912 / 4);
    k_cast<<<1024, 256, 0, stream>>>(preW, PreLatB, 262144);
    k_cast<<<1024, 256, 0, stream>>>(dW1 + (size_t)2048 * 1024, LatB, 262144);
    k_transpose<<<dim3(64, 32), dim3(32, 8), 0, stream>>>(encW, 1024, encWbt, 2048);
    k_transpose<<<dim3(64, 32), dim3(32, 8), 0, stream>>>(tW1, 1024, l1B, 2048);
    k_transpose<<<dim3(64, 32), dim3(32, 8), 0, stream>>>(rW1, 1024, l1B + (size_t)1024 * 2048, 2048);
    k_transpose<<<dim3(32, 32), dim3(32, 8), 0, stream>>>(tW2, 1024, tW2bt, 1024);
    k_transpose<<<dim3(32, 32), dim3(32, 8), 0, stream>>>(rW2, 1024, rW2bt, 1024);
    k_transpose<<<dim3(32, 32), dim3(32, 8), 0, stream>>>(rW1 + (size_t)2048 * 1024, 1024, rW1bbt, 1024);
    k_transpose<<<dim3(64, 32), dim3(32, 8), 0, stream>>>(dW1, 1024, dW1abt, 2048);
    k_transpose<<<dim3(32, 64), dim3(32, 8), 0, stream>>>(dW2, 2048, dW2bt, 1024);

    // phase 1: encoder (4 passes of 4096 rows) + embR precompute
    for (int pass = 0; pass < 4; ++pass) {
        k_prep<<<8192, 256, 0, stream>>>(zs + (size_t)pass * 4096 * 2048, zmean, zstd, flatc);
        GP e{}; e.A = flatc; e.lda = 2048; e.Bt = encWbt; e.Cb = enc + (size_t)pass * 4096 * 1024;
        e.ldc = 1024; e.bias = encb; e.K = 2048; e.gridN = 8;
        gemm_k<4, 4, 1, false><<<dim3(256), 256, 0, stream>>>(e, e);
    }
    {
        GP e{}; e.A = enc; e.lda = 1024; e.Bt = rW1bbt; e.Cb = embR; e.ldc = 1024;
        e.bias = rb1; e.K = 1024; e.gridN = 8;
        gemm_k<4, 4, 2, false><<<dim3(1024), 256, 0, stream>>>(e, e);
    }

    // phase 2: sequential scan (post-only path; prior deferred)
    k_xpre0<<<256, 256, 0, stream>>>(preW, preb, actions, x_bf);
    for (int t = 0; t < 63; ++t) {
        // k1: gx + GRU -> h_t
        if (t == 0)
            k_gates<true><<<256, 256, 0, stream>>>(x_bf, WihB, bih, bhh, GHb, hf32, Hall);
        else
            k_gates<false><<<256, 256, 0, stream>>>(x_bf, WihB, bih, bhh, GHb + (size_t)(t & 1) * 256 * 6144,
                                                    hf32, Hall + (size_t)t * 256 * 2048);
        // k2: gh(t+1) (bf16) || l1-post(t)
        {
            GP pa{}; pa.A = Hall + (size_t)t * 256 * 2048; pa.lda = 2048; pa.Bt = WhhB;
            pa.Cb = GHb + (size_t)((t + 1) & 1) * 256 * 6144; pa.ldc = 6144; pa.bias = bhh;
            pa.K = 2048; pa.gridN = 96;
            GP pb{}; pb.A = Hall + (size_t)t * 256 * 2048; pb.lda = 2048;
            pb.Bt = l1B + (size_t)1024 * 2048; pb.Cb = p1q1; pb.ldc = 1024;
            pb.aux = embR + (size_t)(t + 1) * 1024; pb.auxld = 65536;
            pb.K = 2048; pb.gridN = 16;
            int nA = (t < 62) ? 384 : 0;
            gemmS<2, 2, 2, 2, 7, 4><<<dim3(nA + 64), 256, 0, stream>>>(pa, pb, nA);
        }
        // k3: q-post -> PoAll[t] (bf16) + fused argmax -> latidx[t]
        {
            GP q{}; q.A = p1q1; q.lda = 1024; q.Bt = rW2bt; q.ldc = 1024;
            q.Cb = PoAll + (size_t)t * 256 * 1024; q.bias = rb2; q.K = 1024; q.gridN = 16;
            q.idx = latidx + (size_t)t * 256 * 32;
            gemmS<2, 2, 2, 2, 8, 8><<<dim3(64), 256, 0, stream>>>(q, q, 64);
        }
        // k4: next x from latidx
        if (t < 62)
            k_xgen<<<256, 256, 0, stream>>>(latidx + (size_t)t * 256 * 32,
                                            PreLatB, preW, preb, actions, x_bf, t + 1);
    }

    // phase 3a: batched prior (2 halves of 8064 rows) + KL
    for (int half = 0; half < 2; ++half) {
        int m0 = half * 8064;
        GP e{}; e.A = Hall + (size_t)m0 * 2048; e.lda = 2048; e.Bt = l1B; e.Cb = Xp; e.ldc = 1024;
        e.bias = tb1; e.K = 2048; e.gridN = 8;
        gemm_k<4, 4, 1, false><<<dim3(504), 256, 0, stream>>>(e, e);
        GP q{}; q.A = Xp; q.lda = 1024; q.Bt = tW2bt; q.Cb = PrAll + (size_t)m0 * 1024; q.ldc = 1024;
        q.bias = tb2; q.K = 1024; q.gridN = 8;
        gemm_k<4, 4, 2, false><<<dim3(504), 256, 0, stream>>>(q, q);
    }
    k_kl<<<16128, 256, 0, stream>>>(PoAll, PrAll, klrow);

    // phase 3b: decoder + fused recon (2 halves; latsum overwrites embR/PrAll after k_kl)
    k_latsum<<<16128, 256, 0, stream>>>(LatB, db1, latidx, embR);
    for (int half = 0; half < 2; ++half) {
        int m0 = half * 8064;
        GP d{}; d.A = Hall + (size_t)m0 * 2048; d.lda = 2048; d.Bt = dW1abt; d.Cb = d1; d.ldc = 1024;
        d.aux = embR + (size_t)m0 * 1024; d.auxld = 1024; d.K = 2048; d.gridN = 8;
        gemm_k<4, 4, 4, false><<<dim3(504), 256, 0, stream>>>(d, d);
        GP d2{}; d2.A = d1; d2.lda = 1024; d2.Bt = dW2bt; d2.ldc = 2048; d2.bias = db2;
        d2.zs = zs; d2.zmean = zmean; d2.zstd = zstd; d2.accum = accum; d2.K = 1024; d2.gridN = 16;
        d2.rbase = m0;
        gemm_k<4, 4, 5, false><<<dim3(1008), 256, 0, stream>>>(d2, d2);
    }
    k_finalize<<<1, 256, 0, stream>>>(accum, klrow, (float*)d_out);
}